// Round 1
// baseline (2502.999 us; speedup 1.0000x reference)
//
#include <hip/hip_runtime.h>

#define EPSV 1e-5f

// ---------------- degree / CSR construction ----------------

__global__ void k_init_deg(int* __restrict__ deg, int N) {
    int n = blockIdx.x * blockDim.x + threadIdx.x;
    if (n < N) deg[n] = 1;  // self loop
}

__global__ void k_count(const int* __restrict__ dst, int E, int* __restrict__ deg) {
    int e = blockIdx.x * blockDim.x + threadIdx.x;
    if (e < E) atomicAdd(&deg[dst[e]], 1);
}

__global__ void k_disqrt(const int* __restrict__ deg, float* __restrict__ disq, int N) {
    int n = blockIdx.x * blockDim.x + threadIdx.x;
    if (n < N) disq[n] = rsqrtf((float)deg[n]);  // deg >= 1 always
}

// inclusive per-block scan of deg -> incl, block totals -> bsum
__global__ void k_scan1(const int* __restrict__ deg, int N,
                        int* __restrict__ incl, int* __restrict__ bsum) {
    __shared__ int s[256];
    int n = blockIdx.x * 256 + threadIdx.x;
    s[threadIdx.x] = (n < N) ? deg[n] : 0;
    __syncthreads();
    for (int off = 1; off < 256; off <<= 1) {
        int v = (threadIdx.x >= off) ? s[threadIdx.x - off] : 0;
        __syncthreads();
        s[threadIdx.x] += v;
        __syncthreads();
    }
    if (n < N) incl[n] = s[threadIdx.x];
    if (threadIdx.x == 255) bsum[blockIdx.x] = s[255];
}

__global__ void k_scan2(const int* __restrict__ bsum, int NB, int* __restrict__ boff) {
    if (blockIdx.x == 0 && threadIdx.x == 0) {
        int run = 0;
        for (int b = 0; b < NB; ++b) { boff[b] = run; run += bsum[b]; }
    }
}

// convert to exclusive global offsets; rs may alias incl (read-before-write per thread)
__global__ void k_scan3(const int* __restrict__ deg, const int* __restrict__ incl,
                        const int* __restrict__ boff, int N,
                        int* __restrict__ rs, int* __restrict__ cur) {
    int n = blockIdx.x * 256 + threadIdx.x;
    if (n < N) {
        int v = incl[n] - deg[n] + boff[blockIdx.x];
        rs[n] = v;
        cur[n] = v;
    }
}

__global__ void k_fill(const int* __restrict__ src, const int* __restrict__ dst,
                       int E, int N, const float* __restrict__ disq,
                       int* __restrict__ cur, int* __restrict__ csr_s,
                       float* __restrict__ csr_w) {
    int i = blockIdx.x * blockDim.x + threadIdx.x;
    int total = E + N;
    if (i >= total) return;
    int s, d;
    if (i < E) { s = src[i]; d = dst[i]; }
    else       { s = i - E; d = s; }      // self loops
    int slot = atomicAdd(&cur[d], 1);
    csr_s[slot] = s;
    csr_w[slot] = disq[s] * disq[d];
}

// ---------------- BatchNorm (training-mode batch stats) ----------------

__global__ void k_bnstats(const float* __restrict__ H, int N, int C,
                          float* __restrict__ colsum, float* __restrict__ colsq) {
    __shared__ float ssum[199];
    __shared__ float ssq[199];
    for (int i = threadIdx.x; i < C; i += blockDim.x) { ssum[i] = 0.f; ssq[i] = 0.f; }
    __syncthreads();
    int r0 = blockIdx.x * 256;
    int rows = N - r0; if (rows > 256) rows = 256;
    const float* base = H + (size_t)r0 * C;
    int total = rows * C;
    for (int idx = threadIdx.x; idx < total; idx += blockDim.x) {
        float v = base[idx];
        int c = idx % C;
        atomicAdd(&ssum[c], v);
        atomicAdd(&ssq[c], v * v);
    }
    __syncthreads();
    for (int i = threadIdx.x; i < C; i += blockDim.x) {
        atomicAdd(&colsum[i], ssum[i]);
        atomicAdd(&colsq[i], ssq[i]);
    }
}

__global__ void k_bnfinal(const float* __restrict__ colsum, const float* __restrict__ colsq,
                          int C, float invN, float* __restrict__ meanv, float* __restrict__ rstdv) {
    int i = threadIdx.x;
    if (i < C) {
        float m = colsum[i] * invN;
        float v = colsq[i] * invN - m * m;
        meanv[i] = m;
        rstdv[i] = rsqrtf(fmaxf(v, 0.f) + EPSV);
    }
}

__global__ void k_bnapply(const float* __restrict__ in, float* __restrict__ out,
                          const float* __restrict__ meanv, const float* __restrict__ rstdv,
                          const float* __restrict__ g, const float* __restrict__ b,
                          int total, int C) {
    int idx = blockIdx.x * blockDim.x + threadIdx.x;
    if (idx >= total) return;
    int c = idx % C;
    out[idx] = (in[idx] - meanv[c]) * rstdv[c] * g[c] + b[c];
}

// ---------------- dense GEMM: out[N,Cout] = H[N,Cin] @ W[Cin,Cout] ----------------

__global__ void k_gemm(const float* __restrict__ H, const float* __restrict__ W,
                       float* __restrict__ out, int N, int Cin, int Cout) {
    int idx = blockIdx.x * blockDim.x + threadIdx.x;
    if (idx >= N * Cout) return;
    int n = idx / Cout;
    int j = idx - n * Cout;
    const float* h = H + (size_t)n * Cin;
    float acc = 0.f;
#pragma unroll 4
    for (int k = 0; k < Cin; ++k) acc += h[k] * W[k * Cout + j];
    out[idx] = acc;
}

// ---------------- GCN aggregation (gather over CSR-by-dst) + bias + relu ----------------

__global__ void k_aggregate(const float* __restrict__ A, const int* __restrict__ rs,
                            const int* __restrict__ deg, const int* __restrict__ csr_s,
                            const float* __restrict__ csr_w, const float* __restrict__ bias,
                            float* __restrict__ out, int C) {
    int n = blockIdx.x;
    int j = threadIdx.x;
    int e0 = rs[n];
    int d  = deg[n];
    if (j >= C) return;
    float acc = bias[j];
    for (int e = e0; e < e0 + d; ++e) {
        int s = csr_s[e];
        float w = csr_w[e];
        acc += w * A[s * C + j];
    }
    out[n * C + j] = fmaxf(acc, 0.f);
}

// ---------------- mean pool (batch is sorted) ----------------

__global__ void k_pool(const float* __restrict__ H, const int* __restrict__ batch,
                       int N, int C, float* __restrict__ pooled) {
    __shared__ int sb[256];
    int r0 = blockIdx.x * 256;
    int rows = N - r0; if (rows > 256) rows = 256;
    if (threadIdx.x < rows) sb[threadIdx.x] = batch[r0 + threadIdx.x];
    __syncthreads();
    int c = threadIdx.x;
    if (c >= C) return;
    int cg = sb[0];
    float acc = 0.f;
    for (int r = 0; r < rows; ++r) {
        int g = sb[r];
        if (g != cg) { atomicAdd(&pooled[cg * C + c], acc); acc = 0.f; cg = g; }
        acc += H[(r0 + r) * C + c];
    }
    atomicAdd(&pooled[cg * C + c], acc);
}

__global__ void k_bounds(const int* __restrict__ batch, int N,
                         int* __restrict__ gstart, int* __restrict__ gend) {
    int n = blockIdx.x * blockDim.x + threadIdx.x;
    if (n >= N) return;
    int g = batch[n];
    if (n == 0 || batch[n - 1] != g) gstart[g] = n;
    if (n == N - 1 || batch[n + 1] != g) gend[g] = n + 1;
}

// ---------------- head MLP: (pooled/cnt) @ Wl1 + bl1 -> @ Wl2 + bl2 ----------------

__global__ void k_mlp(const float* __restrict__ pooled, const int* __restrict__ gstart,
                      const int* __restrict__ gend,
                      const float* __restrict__ Wl1, const float* __restrict__ bl1,
                      const float* __restrict__ Wl2, const float* __restrict__ bl2,
                      float* __restrict__ out, int C) {
    __shared__ float p[199];
    __shared__ float t1[49];
    int g = blockIdx.x;
    int cnt = gend[g] - gstart[g];
    float inv = 1.f / (float)(cnt > 1 ? cnt : 1);
    for (int k = threadIdx.x; k < C; k += blockDim.x) p[k] = pooled[g * C + k] * inv;
    __syncthreads();
    if (threadIdx.x < 49) {
        float acc = bl1[threadIdx.x];
        for (int k = 0; k < C; ++k) acc += p[k] * Wl1[k * 49 + threadIdx.x];
        t1[threadIdx.x] = acc;
    }
    __syncthreads();
    if (threadIdx.x < 2) {
        float acc = bl2[threadIdx.x];
        for (int k = 0; k < 49; ++k) acc += t1[k] * Wl2[k * 2 + threadIdx.x];
        out[g * 2 + threadIdx.x] = acc;
    }
}

// ---------------- launch ----------------

extern "C" void kernel_launch(void* const* d_in, const int* in_sizes, int n_in,
                              void* d_out, int out_size, void* d_ws, size_t ws_size,
                              hipStream_t stream) {
    const float* x     = (const float*)d_in[0];
    const int*   ei    = (const int*)d_in[1];
    const int*   batch = (const int*)d_in[2];
    const float* bn0g = (const float*)d_in[3];
    const float* bn0b = (const float*)d_in[4];
    const float* bn1g = (const float*)d_in[5];
    const float* bn1b = (const float*)d_in[6];
    const float* bn2g = (const float*)d_in[7];
    const float* bn2b = (const float*)d_in[8];
    const float* W1  = (const float*)d_in[9];
    const float* b1  = (const float*)d_in[10];
    const float* W2  = (const float*)d_in[11];
    const float* b2  = (const float*)d_in[12];
    const float* W3  = (const float*)d_in[13];
    const float* b3  = (const float*)d_in[14];
    const float* Wl1 = (const float*)d_in[15];
    const float* bl1 = (const float*)d_in[16];
    const float* Wl2 = (const float*)d_in[17];
    const float* bl2 = (const float*)d_in[18];

    const int N = in_sizes[0] / 7;
    const int E = in_sizes[1] / 2;
    const int EN = E + N;
    const int G = out_size / 2;       // 256 graphs
    const int NB = (N + 255) / 256;

    const int* src = ei;
    const int* dst = ei + E;

    // workspace carve-up (all 256B-aligned)
    char* w = (char*)d_ws;
    auto alloc = [&](size_t bytes) -> void* {
        void* p = (void*)w;
        w += ((bytes + 255) / 256) * 256;
        return p;
    };
    float* bufA  = (float*)alloc((size_t)N * 199 * sizeof(float));
    float* bufB  = (float*)alloc((size_t)N * 199 * sizeof(float));
    float* disq  = (float*)alloc((size_t)N * sizeof(float));
    int*   deg   = (int*)  alloc((size_t)N * sizeof(int));
    int*   rs    = (int*)  alloc((size_t)N * sizeof(int));
    int*   cur   = (int*)  alloc((size_t)N * sizeof(int));
    int*   csr_s = (int*)  alloc((size_t)EN * sizeof(int));
    float* csr_w = (float*)alloc((size_t)EN * sizeof(float));
    float* colsum= (float*)alloc(256 * sizeof(float));
    float* colsq = (float*)alloc(256 * sizeof(float));
    float* meanv = (float*)alloc(256 * sizeof(float));
    float* rstdv = (float*)alloc(256 * sizeof(float));
    float* pooled= (float*)alloc((size_t)G * 199 * sizeof(float));
    int*   gstart= (int*)  alloc((size_t)G * sizeof(int));
    int*   gend  = (int*)  alloc((size_t)G * sizeof(int));
    int*   bsum  = (int*)  alloc((size_t)NB * sizeof(int));
    int*   boff  = (int*)  alloc((size_t)NB * sizeof(int));

    // ---- degree + CSR (built once, reused by all 3 layers) ----
    k_init_deg<<<(N + 255) / 256, 256, 0, stream>>>(deg, N);
    k_count<<<(E + 255) / 256, 256, 0, stream>>>(dst, E, deg);
    k_disqrt<<<(N + 255) / 256, 256, 0, stream>>>(deg, disq, N);
    k_scan1<<<NB, 256, 0, stream>>>(deg, N, rs, bsum);
    k_scan2<<<1, 1, 0, stream>>>(bsum, NB, boff);
    k_scan3<<<NB, 256, 0, stream>>>(deg, rs, boff, N, rs, cur);
    k_fill<<<(EN + 255) / 256, 256, 0, stream>>>(src, dst, E, N, disq, cur, csr_s, csr_w);

    auto bn = [&](const float* in, float* out, const float* g, const float* b, int C) {
        hipMemsetAsync(colsum, 0, C * sizeof(float), stream);
        hipMemsetAsync(colsq, 0, C * sizeof(float), stream);
        k_bnstats<<<NB, 256, 0, stream>>>(in, N, C, colsum, colsq);
        k_bnfinal<<<1, 256, 0, stream>>>(colsum, colsq, C, 1.f / (float)N, meanv, rstdv);
        int total = N * C;
        k_bnapply<<<(total + 255) / 256, 256, 0, stream>>>(in, out, meanv, rstdv, g, b, total, C);
    };

    // ---- layer 1 ----
    bn(x, bufB, bn0g, bn0b, 7);
    k_gemm<<<(N * 71 + 255) / 256, 256, 0, stream>>>(bufB, W1, bufA, N, 7, 71);
    k_aggregate<<<N, 128, 0, stream>>>(bufA, rs, deg, csr_s, csr_w, b1, bufB, 71);
    // ---- layer 2 ----
    bn(bufB, bufB, bn1g, bn1b, 71);
    k_gemm<<<(N * 135 + 255) / 256, 256, 0, stream>>>(bufB, W2, bufA, N, 71, 135);
    k_aggregate<<<N, 192, 0, stream>>>(bufA, rs, deg, csr_s, csr_w, b2, bufB, 135);
    // ---- layer 3 ----
    bn(bufB, bufB, bn2g, bn2b, 135);
    k_gemm<<<(N * 199 + 255) / 256, 256, 0, stream>>>(bufB, W3, bufA, N, 135, 199);
    k_aggregate<<<N, 256, 0, stream>>>(bufA, rs, deg, csr_s, csr_w, b3, bufB, 199);

    // ---- pool + head ----
    hipMemsetAsync(pooled, 0, (size_t)G * 199 * sizeof(float), stream);
    hipMemsetAsync(gstart, 0, G * sizeof(int), stream);
    hipMemsetAsync(gend, 0, G * sizeof(int), stream);
    k_pool<<<NB, 256, 0, stream>>>(bufB, batch, N, 199, pooled);
    k_bounds<<<(N + 255) / 256, 256, 0, stream>>>(batch, N, gstart, gend);
    k_mlp<<<G, 64, 0, stream>>>(pooled, gstart, gend, Wl1, bl1, Wl2, bl2, (float*)d_out, 199);
}

// Round 2
// 1664.159 us; speedup vs baseline: 1.5041x; 1.5041x over previous
//
#include <hip/hip_runtime.h>

#define EPSV 1e-5f

// ---------------- degree / CSR construction ----------------

__global__ void k_init_deg(int* __restrict__ deg, int N) {
    int n = blockIdx.x * blockDim.x + threadIdx.x;
    if (n < N) deg[n] = 1;  // self loop
}

__global__ void k_count(const int* __restrict__ dst, int E, int* __restrict__ deg) {
    int e = blockIdx.x * blockDim.x + threadIdx.x;
    if (e < E) atomicAdd(&deg[dst[e]], 1);
}

__global__ void k_disqrt(const int* __restrict__ deg, float* __restrict__ disq, int N) {
    int n = blockIdx.x * blockDim.x + threadIdx.x;
    if (n < N) disq[n] = rsqrtf((float)deg[n]);  // deg >= 1 always
}

// inclusive per-block scan of deg -> incl, block totals -> bsum
__global__ void k_scan1(const int* __restrict__ deg, int N,
                        int* __restrict__ incl, int* __restrict__ bsum) {
    __shared__ int s[256];
    int n = blockIdx.x * 256 + threadIdx.x;
    s[threadIdx.x] = (n < N) ? deg[n] : 0;
    __syncthreads();
    for (int off = 1; off < 256; off <<= 1) {
        int v = (threadIdx.x >= off) ? s[threadIdx.x - off] : 0;
        __syncthreads();
        s[threadIdx.x] += v;
        __syncthreads();
    }
    if (n < N) incl[n] = s[threadIdx.x];
    if (threadIdx.x == 255) bsum[blockIdx.x] = s[255];
}

__global__ void k_scan2(const int* __restrict__ bsum, int NB, int* __restrict__ boff) {
    if (blockIdx.x == 0 && threadIdx.x == 0) {
        int run = 0;
        for (int b = 0; b < NB; ++b) { boff[b] = run; run += bsum[b]; }
    }
}

__global__ void k_scan3(const int* __restrict__ deg, const int* __restrict__ incl,
                        const int* __restrict__ boff, int N,
                        int* __restrict__ rs, int* __restrict__ cur) {
    int n = blockIdx.x * 256 + threadIdx.x;
    if (n < N) {
        int v = incl[n] - deg[n] + boff[blockIdx.x];
        rs[n] = v;
        cur[n] = v;
    }
}

__global__ void k_fill(const int* __restrict__ src, const int* __restrict__ dst,
                       int E, int N, const float* __restrict__ disq,
                       int* __restrict__ cur, int* __restrict__ csr_s,
                       float* __restrict__ csr_w) {
    int i = blockIdx.x * blockDim.x + threadIdx.x;
    int total = E + N;
    if (i >= total) return;
    int s, d;
    if (i < E) { s = src[i]; d = dst[i]; }
    else       { s = i - E; d = s; }      // self loops
    int slot = atomicAdd(&cur[d], 1);
    csr_s[slot] = s;
    csr_w[slot] = disq[s] * disq[d];
}

// ---------------- BatchNorm stats (no LDS atomics: column-per-thread regs) ----

__global__ void k_bnstats(const float* __restrict__ H, int N, int C,
                          float* __restrict__ colsum, float* __restrict__ colsq) {
    int j = threadIdx.x;
    if (j >= C) return;
    int r0 = blockIdx.x * 256;
    int rend = r0 + 256; if (rend > N) rend = N;
    float s = 0.f, q = 0.f;
    for (int r = r0; r < rend; ++r) {
        float v = H[(size_t)r * C + j];
        s += v;
        q += v * v;
    }
    atomicAdd(&colsum[j], s);
    atomicAdd(&colsq[j], q);
}

// scale/shift so BN folds into the GEMM A-load: a = v*scale[k] + shift[k]
__global__ void k_bnfinal(const float* __restrict__ colsum, const float* __restrict__ colsq,
                          const float* __restrict__ g, const float* __restrict__ b,
                          int C, float invN,
                          float* __restrict__ scale, float* __restrict__ shift) {
    int i = threadIdx.x;
    if (i < C) {
        float m = colsum[i] * invN;
        float v = colsq[i] * invN - m * m;
        float rstd = rsqrtf(fmaxf(v, 0.f) + EPSV);
        float sc = rstd * g[i];
        scale[i] = sc;
        shift[i] = b[i] - m * sc;
    }
}

// ---------------- tiled GEMM with fused BN on A: out = bn(H) @ W ----------------
// 64x64 output tile, 16x16 threads, 4x4 accum/thread, TK=16.

#define TM 64
#define TN 64
#define TK 16

__global__ __launch_bounds__(256) void k_gemm_bn(
    const float* __restrict__ H, const float* __restrict__ W,
    const float* __restrict__ scale, const float* __restrict__ shift,
    float* __restrict__ out, int N, int Cin, int Cout) {
    __shared__ float As[TK][TM + 4];   // transposed A tile: As[k][m]; +4 pad (bank + b128 align)
    __shared__ float Bs[TK][TN];
    const int r0 = blockIdx.x * TM;
    const int c0 = blockIdx.y * TN;
    const int t = threadIdx.x;
    const int tx = t & 15;             // output col group
    const int ty = t >> 4;             // output row group
    float acc[4][4] = {};

    for (int k0 = 0; k0 < Cin; k0 += TK) {
        // A tile: rows r0..r0+63, cols k0..k0+15 ; each thread 4 elems
        {
            int col = t & 15;          // k within tile
            int rbase = t >> 4;        // 0..15
#pragma unroll
            for (int i = 0; i < 4; ++i) {
                int row = rbase + i * 16;          // 0..63
                int gr = r0 + row;
                int gk = k0 + col;
                float v = 0.f;
                if (gr < N && gk < Cin)
                    v = H[(size_t)gr * Cin + gk] * scale[gk] + shift[gk];
                As[col][row] = v;
            }
        }
        // B tile: rows k0..k0+15, cols c0..c0+63 ; each thread 4 elems
        {
            int col = t & 63;
            int kb  = t >> 6;          // 0..3
#pragma unroll
            for (int i = 0; i < 4; ++i) {
                int k = kb + i * 4;    // 0..15
                int gk = k0 + k;
                int gc = c0 + col;
                float v = 0.f;
                if (gk < Cin && gc < Cout)
                    v = W[(size_t)gk * Cout + gc];
                Bs[k][col] = v;
            }
        }
        __syncthreads();
#pragma unroll
        for (int k = 0; k < TK; ++k) {
            float4 a = *(const float4*)&As[k][ty * 4];
            float4 b = *(const float4*)&Bs[k][tx * 4];
            float av[4] = {a.x, a.y, a.z, a.w};
            float bv[4] = {b.x, b.y, b.z, b.w};
#pragma unroll
            for (int i = 0; i < 4; ++i)
#pragma unroll
                for (int j = 0; j < 4; ++j)
                    acc[i][j] = fmaf(av[i], bv[j], acc[i][j]);
        }
        __syncthreads();
    }

#pragma unroll
    for (int i = 0; i < 4; ++i) {
        int gr = r0 + ty * 4 + i;
        if (gr >= N) continue;
#pragma unroll
        for (int j = 0; j < 4; ++j) {
            int gc = c0 + tx * 4 + j;
            if (gc < Cout) out[(size_t)gr * Cout + gc] = acc[i][j];
        }
    }
}

// ---------------- GCN aggregation (gather over CSR-by-dst) + bias + relu ----------------

__global__ void k_aggregate(const float* __restrict__ A, const int* __restrict__ rs,
                            const int* __restrict__ deg, const int* __restrict__ csr_s,
                            const float* __restrict__ csr_w, const float* __restrict__ bias,
                            float* __restrict__ out, int C) {
    int n = blockIdx.x;
    int j = threadIdx.x;
    int e0 = rs[n];
    int d  = deg[n];
    if (j >= C) return;
    float acc = bias[j];
    for (int e = e0; e < e0 + d; ++e) {
        int s = csr_s[e];
        float w = csr_w[e];
        acc += w * A[(size_t)s * C + j];
    }
    out[(size_t)n * C + j] = fmaxf(acc, 0.f);
}

// ---------------- mean pool (batch is sorted) ----------------

__global__ void k_pool(const float* __restrict__ H, const int* __restrict__ batch,
                       int N, int C, float* __restrict__ pooled) {
    __shared__ int sb[256];
    int r0 = blockIdx.x * 256;
    int rows = N - r0; if (rows > 256) rows = 256;
    if (threadIdx.x < rows) sb[threadIdx.x] = batch[r0 + threadIdx.x];
    __syncthreads();
    int c = threadIdx.x;
    if (c >= C) return;
    int cg = sb[0];
    float acc = 0.f;
    for (int r = 0; r < rows; ++r) {
        int g = sb[r];
        if (g != cg) { atomicAdd(&pooled[cg * C + c], acc); acc = 0.f; cg = g; }
        acc += H[(size_t)(r0 + r) * C + c];
    }
    atomicAdd(&pooled[cg * C + c], acc);
}

__global__ void k_bounds(const int* __restrict__ batch, int N,
                         int* __restrict__ gstart, int* __restrict__ gend) {
    int n = blockIdx.x * blockDim.x + threadIdx.x;
    if (n >= N) return;
    int g = batch[n];
    if (n == 0 || batch[n - 1] != g) gstart[g] = n;
    if (n == N - 1 || batch[n + 1] != g) gend[g] = n + 1;
}

// ---------------- head MLP ----------------

__global__ void k_mlp(const float* __restrict__ pooled, const int* __restrict__ gstart,
                      const int* __restrict__ gend,
                      const float* __restrict__ Wl1, const float* __restrict__ bl1,
                      const float* __restrict__ Wl2, const float* __restrict__ bl2,
                      float* __restrict__ out, int C) {
    __shared__ float p[199];
    __shared__ float t1[49];
    int g = blockIdx.x;
    int cnt = gend[g] - gstart[g];
    float inv = 1.f / (float)(cnt > 1 ? cnt : 1);
    for (int k = threadIdx.x; k < C; k += blockDim.x) p[k] = pooled[g * C + k] * inv;
    __syncthreads();
    if (threadIdx.x < 49) {
        float acc = bl1[threadIdx.x];
        for (int k = 0; k < C; ++k) acc += p[k] * Wl1[k * 49 + threadIdx.x];
        t1[threadIdx.x] = acc;
    }
    __syncthreads();
    if (threadIdx.x < 2) {
        float acc = bl2[threadIdx.x];
        for (int k = 0; k < 49; ++k) acc += t1[k] * Wl2[k * 2 + threadIdx.x];
        out[g * 2 + threadIdx.x] = acc;
    }
}

// ---------------- launch ----------------

extern "C" void kernel_launch(void* const* d_in, const int* in_sizes, int n_in,
                              void* d_out, int out_size, void* d_ws, size_t ws_size,
                              hipStream_t stream) {
    const float* x     = (const float*)d_in[0];
    const int*   ei    = (const int*)d_in[1];
    const int*   batch = (const int*)d_in[2];
    const float* bn0g = (const float*)d_in[3];
    const float* bn0b = (const float*)d_in[4];
    const float* bn1g = (const float*)d_in[5];
    const float* bn1b = (const float*)d_in[6];
    const float* bn2g = (const float*)d_in[7];
    const float* bn2b = (const float*)d_in[8];
    const float* W1  = (const float*)d_in[9];
    const float* b1  = (const float*)d_in[10];
    const float* W2  = (const float*)d_in[11];
    const float* b2  = (const float*)d_in[12];
    const float* W3  = (const float*)d_in[13];
    const float* b3  = (const float*)d_in[14];
    const float* Wl1 = (const float*)d_in[15];
    const float* bl1 = (const float*)d_in[16];
    const float* Wl2 = (const float*)d_in[17];
    const float* bl2 = (const float*)d_in[18];

    const int N = in_sizes[0] / 7;
    const int E = in_sizes[1] / 2;
    const int EN = E + N;
    const int G = out_size / 2;
    const int NB = (N + 255) / 256;

    const int* src = ei;
    const int* dst = ei + E;

    char* w = (char*)d_ws;
    auto alloc = [&](size_t bytes) -> void* {
        void* p = (void*)w;
        w += ((bytes + 255) / 256) * 256;
        return p;
    };
    float* bufA  = (float*)alloc((size_t)N * 199 * sizeof(float));
    float* bufB  = (float*)alloc((size_t)N * 199 * sizeof(float));
    float* disq  = (float*)alloc((size_t)N * sizeof(float));
    int*   deg   = (int*)  alloc((size_t)N * sizeof(int));
    int*   rs    = (int*)  alloc((size_t)N * sizeof(int));
    int*   cur   = (int*)  alloc((size_t)N * sizeof(int));
    int*   csr_s = (int*)  alloc((size_t)EN * sizeof(int));
    float* csr_w = (float*)alloc((size_t)EN * sizeof(float));
    float* colsum= (float*)alloc(256 * sizeof(float));
    float* colsq = (float*)alloc(256 * sizeof(float));
    float* scale = (float*)alloc(256 * sizeof(float));
    float* shift = (float*)alloc(256 * sizeof(float));
    float* pooled= (float*)alloc((size_t)G * 199 * sizeof(float));
    int*   gstart= (int*)  alloc((size_t)G * sizeof(int));
    int*   gend  = (int*)  alloc((size_t)G * sizeof(int));
    int*   bsum  = (int*)  alloc((size_t)NB * sizeof(int));
    int*   boff  = (int*)  alloc((size_t)NB * sizeof(int));

    // ---- degree + CSR (built once, reused by all 3 layers) ----
    k_init_deg<<<(N + 255) / 256, 256, 0, stream>>>(deg, N);
    k_count<<<(E + 255) / 256, 256, 0, stream>>>(dst, E, deg);
    k_disqrt<<<(N + 255) / 256, 256, 0, stream>>>(deg, disq, N);
    k_scan1<<<NB, 256, 0, stream>>>(deg, N, rs, bsum);
    k_scan2<<<1, 1, 0, stream>>>(bsum, NB, boff);
    k_scan3<<<NB, 256, 0, stream>>>(deg, rs, boff, N, rs, cur);
    k_fill<<<(EN + 255) / 256, 256, 0, stream>>>(src, dst, E, N, disq, cur, csr_s, csr_w);

    auto bn_gemm = [&](const float* Hin, const float* g, const float* b,
                       const float* Wm, float* Hout, int Cin, int Cout) {
        hipMemsetAsync(colsum, 0, Cin * sizeof(float), stream);
        hipMemsetAsync(colsq, 0, Cin * sizeof(float), stream);
        k_bnstats<<<NB, 256, 0, stream>>>(Hin, N, Cin, colsum, colsq);
        k_bnfinal<<<1, 256, 0, stream>>>(colsum, colsq, g, b, Cin, 1.f / (float)N, scale, shift);
        dim3 grid((N + TM - 1) / TM, (Cout + TN - 1) / TN);
        k_gemm_bn<<<grid, 256, 0, stream>>>(Hin, Wm, scale, shift, Hout, N, Cin, Cout);
    };

    // ---- layer 1 ----
    bn_gemm(x, bn0g, bn0b, W1, bufA, 7, 71);
    k_aggregate<<<N, 128, 0, stream>>>(bufA, rs, deg, csr_s, csr_w, b1, bufB, 71);
    // ---- layer 2 ----
    bn_gemm(bufB, bn1g, bn1b, W2, bufA, 71, 135);
    k_aggregate<<<N, 192, 0, stream>>>(bufA, rs, deg, csr_s, csr_w, b2, bufB, 135);
    // ---- layer 3 ----
    bn_gemm(bufB, bn2g, bn2b, W3, bufA, 135, 199);
    k_aggregate<<<N, 256, 0, stream>>>(bufA, rs, deg, csr_s, csr_w, b3, bufB, 199);

    // ---- pool + head ----
    hipMemsetAsync(pooled, 0, (size_t)G * 199 * sizeof(float), stream);
    hipMemsetAsync(gstart, 0, G * sizeof(int), stream);
    hipMemsetAsync(gend, 0, G * sizeof(int), stream);
    k_pool<<<NB, 256, 0, stream>>>(bufB, batch, N, 199, pooled);
    k_bounds<<<(N + 255) / 256, 256, 0, stream>>>(batch, N, gstart, gend);
    k_mlp<<<G, 64, 0, stream>>>(pooled, gstart, gend, Wl1, bl1, Wl2, bl2, (float*)d_out, 199);
}

// Round 3
// 1139.658 us; speedup vs baseline: 2.1963x; 1.4602x over previous
//
#include <hip/hip_runtime.h>
#include <hip/hip_fp16.h>

#define EPSV 1e-5f

// ---------------- degree / CSR construction ----------------

__global__ void k_init_deg(int* __restrict__ deg, int N) {
    int n = blockIdx.x * blockDim.x + threadIdx.x;
    if (n < N) deg[n] = 1;  // self loop
}

__global__ void k_count(const int* __restrict__ dst, int E, int* __restrict__ deg) {
    int e = blockIdx.x * blockDim.x + threadIdx.x;
    if (e < E) atomicAdd(&deg[dst[e]], 1);
}

__global__ void k_disqrt(const int* __restrict__ deg, float* __restrict__ disq, int N) {
    int n = blockIdx.x * blockDim.x + threadIdx.x;
    if (n < N) disq[n] = rsqrtf((float)deg[n]);  // deg >= 1 always
}

__global__ void k_scan1(const int* __restrict__ deg, int N,
                        int* __restrict__ incl, int* __restrict__ bsum) {
    __shared__ int s[256];
    int n = blockIdx.x * 256 + threadIdx.x;
    s[threadIdx.x] = (n < N) ? deg[n] : 0;
    __syncthreads();
    for (int off = 1; off < 256; off <<= 1) {
        int v = (threadIdx.x >= off) ? s[threadIdx.x - off] : 0;
        __syncthreads();
        s[threadIdx.x] += v;
        __syncthreads();
    }
    if (n < N) incl[n] = s[threadIdx.x];
    if (threadIdx.x == 255) bsum[blockIdx.x] = s[255];
}

__global__ void k_scan2(const int* __restrict__ bsum, int NB, int* __restrict__ boff) {
    if (blockIdx.x == 0 && threadIdx.x == 0) {
        int run = 0;
        for (int b = 0; b < NB; ++b) { boff[b] = run; run += bsum[b]; }
    }
}

__global__ void k_scan3(const int* __restrict__ deg, const int* __restrict__ incl,
                        const int* __restrict__ boff, int N,
                        int* __restrict__ rs, int* __restrict__ cur) {
    int n = blockIdx.x * 256 + threadIdx.x;
    if (n < N) {
        int v = incl[n] - deg[n] + boff[blockIdx.x];
        rs[n] = v;
        cur[n] = v;
    }
}

__global__ void k_fill(const int* __restrict__ src, const int* __restrict__ dst,
                       int E, int N, const float* __restrict__ disq,
                       int* __restrict__ cur, int* __restrict__ csr_s,
                       float* __restrict__ csr_w) {
    int i = blockIdx.x * blockDim.x + threadIdx.x;
    int total = E + N;
    if (i >= total) return;
    int s, d;
    if (i < E) { s = src[i]; d = dst[i]; }
    else       { s = i - E; d = s; }      // self loops
    int slot = atomicAdd(&cur[d], 1);
    csr_s[slot] = s;
    csr_w[slot] = disq[s] * disq[d];
}

// ---------------- BatchNorm stats (register accumulation, strided buffers) ----

__global__ void k_bnstats(const float* __restrict__ H, int N, int C, int SP,
                          float* __restrict__ colsum, float* __restrict__ colsq) {
    int j = threadIdx.x;
    if (j >= C) return;
    int r0 = blockIdx.x * 256;
    int rend = r0 + 256; if (rend > N) rend = N;
    float s = 0.f, q = 0.f;
    for (int r = r0; r < rend; ++r) {
        float v = H[(size_t)r * SP + j];
        s += v;
        q += v * v;
    }
    atomicAdd(&colsum[j], s);
    atomicAdd(&colsq[j], q);
}

// scale/shift so BN folds into the GEMM A-load: a = v*scale[k] + shift[k]
__global__ void k_bnfinal(const float* __restrict__ colsum, const float* __restrict__ colsq,
                          const float* __restrict__ g, const float* __restrict__ b,
                          int C, float invN,
                          float* __restrict__ scale, float* __restrict__ shift) {
    int i = threadIdx.x;
    if (i < C) {
        float m = colsum[i] * invN;
        float v = colsq[i] * invN - m * m;
        float rstd = rsqrtf(fmaxf(v, 0.f) + EPSV);
        float sc = rstd * g[i];
        scale[i] = sc;
        shift[i] = b[i] - m * sc;
    }
}

// ---------------- tiled GEMM with fused BN on A, fp16 output ----------------
// out_h[N, SPo(halfs)] = bn(H[N, strideA]) @ W[Cin, Cout];  pad cols -> 0.

#define TM 64
#define TN 64
#define TK 16

__global__ __launch_bounds__(256) void k_gemm_bn(
    const float* __restrict__ H, int strideA, const float* __restrict__ W,
    const float* __restrict__ scale, const float* __restrict__ shift,
    __half* __restrict__ out, int SPo, int N, int Cin, int Cout) {
    __shared__ float As[TK][TM + 4];
    __shared__ float Bs[TK][TN];
    const int r0 = blockIdx.x * TM;
    const int c0 = blockIdx.y * TN;
    const int t = threadIdx.x;
    const int tx = t & 15;
    const int ty = t >> 4;
    float acc[4][4] = {};

    for (int k0 = 0; k0 < Cin; k0 += TK) {
        {
            int col = t & 15;
            int rbase = t >> 4;
#pragma unroll
            for (int i = 0; i < 4; ++i) {
                int row = rbase + i * 16;
                int gr = r0 + row;
                int gk = k0 + col;
                float v = 0.f;
                if (gr < N && gk < Cin)
                    v = H[(size_t)gr * strideA + gk] * scale[gk] + shift[gk];
                As[col][row] = v;
            }
        }
        {
            int col = t & 63;
            int kb  = t >> 6;
#pragma unroll
            for (int i = 0; i < 4; ++i) {
                int k = kb + i * 4;
                int gk = k0 + k;
                int gc = c0 + col;
                float v = 0.f;
                if (gk < Cin && gc < Cout)      // pad cols get exact 0
                    v = W[(size_t)gk * Cout + gc];
                Bs[k][col] = v;
            }
        }
        __syncthreads();
#pragma unroll
        for (int k = 0; k < TK; ++k) {
            float4 a = *(const float4*)&As[k][ty * 4];
            float4 b = *(const float4*)&Bs[k][tx * 4];
            float av[4] = {a.x, a.y, a.z, a.w};
            float bv[4] = {b.x, b.y, b.z, b.w};
#pragma unroll
            for (int i = 0; i < 4; ++i)
#pragma unroll
                for (int j = 0; j < 4; ++j)
                    acc[i][j] = fmaf(av[i], bv[j], acc[i][j]);
        }
        __syncthreads();
    }

#pragma unroll
    for (int i = 0; i < 4; ++i) {
        int gr = r0 + ty * 4 + i;
        if (gr >= N) continue;
        int gc = c0 + tx * 4;
        if (gc + 4 <= SPo) {
            __half2 h01 = __floats2half2_rn(acc[i][0], acc[i][1]);
            __half2 h23 = __floats2half2_rn(acc[i][2], acc[i][3]);
            float2 packed;
            ((__half2*)&packed)[0] = h01;
            ((__half2*)&packed)[1] = h23;
            *(float2*)(out + (size_t)gr * SPo + gc) = packed;   // 8B aligned
        }
    }
}

// ------- GCN aggregation: one wave per node, fp16 gather, 4-edge unroll -------
// A: fp16 [N, SPh], out: fp32 [N, SPo], bias+relu fused.

__global__ __launch_bounds__(256) void k_aggregate_h(
    const __half* __restrict__ A, int SPh,
    const int* __restrict__ rs, const int* __restrict__ deg,
    const int* __restrict__ csr_s, const float* __restrict__ csr_w,
    const float* __restrict__ bias,
    float* __restrict__ out, int SPo, int N, int C) {
    int wave = threadIdx.x >> 6;
    int lane = threadIdx.x & 63;
    int n = blockIdx.x * 4 + wave;
    if (n >= N) return;
    int c0 = lane * 4;
    bool active = c0 < SPh;            // can read/write 4 cols (SPh mult of 4)
    int cc = active ? c0 : 0;          // clamp inactive lanes to a safe addr

    int e0 = rs[n];
    int eend = e0 + deg[n];
    float acc0 = 0.f, acc1 = 0.f, acc2 = 0.f, acc3 = 0.f;

    int e = e0;
    for (; e + 4 <= eend; e += 4) {
        int s0 = csr_s[e + 0], s1 = csr_s[e + 1], s2 = csr_s[e + 2], s3 = csr_s[e + 3];
        float w0 = csr_w[e + 0], w1 = csr_w[e + 1], w2 = csr_w[e + 2], w3 = csr_w[e + 3];
        float2 r0 = *(const float2*)(A + (size_t)s0 * SPh + cc);
        float2 r1 = *(const float2*)(A + (size_t)s1 * SPh + cc);
        float2 r2 = *(const float2*)(A + (size_t)s2 * SPh + cc);
        float2 r3 = *(const float2*)(A + (size_t)s3 * SPh + cc);
        {
            float2 f01 = __half22float2(((const __half2*)&r0)[0]);
            float2 f23 = __half22float2(((const __half2*)&r0)[1]);
            acc0 = fmaf(w0, f01.x, acc0); acc1 = fmaf(w0, f01.y, acc1);
            acc2 = fmaf(w0, f23.x, acc2); acc3 = fmaf(w0, f23.y, acc3);
        }
        {
            float2 f01 = __half22float2(((const __half2*)&r1)[0]);
            float2 f23 = __half22float2(((const __half2*)&r1)[1]);
            acc0 = fmaf(w1, f01.x, acc0); acc1 = fmaf(w1, f01.y, acc1);
            acc2 = fmaf(w1, f23.x, acc2); acc3 = fmaf(w1, f23.y, acc3);
        }
        {
            float2 f01 = __half22float2(((const __half2*)&r2)[0]);
            float2 f23 = __half22float2(((const __half2*)&r2)[1]);
            acc0 = fmaf(w2, f01.x, acc0); acc1 = fmaf(w2, f01.y, acc1);
            acc2 = fmaf(w2, f23.x, acc2); acc3 = fmaf(w2, f23.y, acc3);
        }
        {
            float2 f01 = __half22float2(((const __half2*)&r3)[0]);
            float2 f23 = __half22float2(((const __half2*)&r3)[1]);
            acc0 = fmaf(w3, f01.x, acc0); acc1 = fmaf(w3, f01.y, acc1);
            acc2 = fmaf(w3, f23.x, acc2); acc3 = fmaf(w3, f23.y, acc3);
        }
    }
    for (; e < eend; ++e) {
        int s = csr_s[e];
        float w = csr_w[e];
        float2 r = *(const float2*)(A + (size_t)s * SPh + cc);
        float2 f01 = __half22float2(((const __half2*)&r)[0]);
        float2 f23 = __half22float2(((const __half2*)&r)[1]);
        acc0 = fmaf(w, f01.x, acc0); acc1 = fmaf(w, f01.y, acc1);
        acc2 = fmaf(w, f23.x, acc2); acc3 = fmaf(w, f23.y, acc3);
    }

    if (active) {
        float b0 = (c0 + 0 < C) ? bias[c0 + 0] : 0.f;
        float b1 = (c0 + 1 < C) ? bias[c0 + 1] : 0.f;
        float b2 = (c0 + 2 < C) ? bias[c0 + 2] : 0.f;
        float b3 = (c0 + 3 < C) ? bias[c0 + 3] : 0.f;
        float4 o;
        o.x = fmaxf(acc0 + b0, 0.f);
        o.y = fmaxf(acc1 + b1, 0.f);
        o.z = fmaxf(acc2 + b2, 0.f);
        o.w = fmaxf(acc3 + b3, 0.f);
        *(float4*)(out + (size_t)n * SPo + c0) = o;   // 16B aligned (SPo, c0 mult of 4)
    }
}

// ---------------- mean pool (batch is sorted) ----------------

__global__ void k_pool(const float* __restrict__ H, int SP, const int* __restrict__ batch,
                       int N, int C, float* __restrict__ pooled) {
    __shared__ int sb[256];
    int r0 = blockIdx.x * 256;
    int rows = N - r0; if (rows > 256) rows = 256;
    if (threadIdx.x < rows) sb[threadIdx.x] = batch[r0 + threadIdx.x];
    __syncthreads();
    int c = threadIdx.x;
    if (c >= C) return;
    int cg = sb[0];
    float acc = 0.f;
    for (int r = 0; r < rows; ++r) {
        int g = sb[r];
        if (g != cg) { atomicAdd(&pooled[cg * C + c], acc); acc = 0.f; cg = g; }
        acc += H[(size_t)(r0 + r) * SP + c];
    }
    atomicAdd(&pooled[cg * C + c], acc);
}

__global__ void k_bounds(const int* __restrict__ batch, int N,
                         int* __restrict__ gstart, int* __restrict__ gend) {
    int n = blockIdx.x * blockDim.x + threadIdx.x;
    if (n >= N) return;
    int g = batch[n];
    if (n == 0 || batch[n - 1] != g) gstart[g] = n;
    if (n == N - 1 || batch[n + 1] != g) gend[g] = n + 1;
}

// ---------------- head MLP ----------------

__global__ void k_mlp(const float* __restrict__ pooled, const int* __restrict__ gstart,
                      const int* __restrict__ gend,
                      const float* __restrict__ Wl1, const float* __restrict__ bl1,
                      const float* __restrict__ Wl2, const float* __restrict__ bl2,
                      float* __restrict__ out, int C) {
    __shared__ float p[199];
    __shared__ float t1[49];
    int g = blockIdx.x;
    int cnt = gend[g] - gstart[g];
    float inv = 1.f / (float)(cnt > 1 ? cnt : 1);
    for (int k = threadIdx.x; k < C; k += blockDim.x) p[k] = pooled[g * C + k] * inv;
    __syncthreads();
    if (threadIdx.x < 49) {
        float acc = bl1[threadIdx.x];
        for (int k = 0; k < C; ++k) acc += p[k] * Wl1[k * 49 + threadIdx.x];
        t1[threadIdx.x] = acc;
    }
    __syncthreads();
    if (threadIdx.x < 2) {
        float acc = bl2[threadIdx.x];
        for (int k = 0; k < 49; ++k) acc += t1[k] * Wl2[k * 2 + threadIdx.x];
        out[g * 2 + threadIdx.x] = acc;
    }
}

// ---------------- launch ----------------

extern "C" void kernel_launch(void* const* d_in, const int* in_sizes, int n_in,
                              void* d_out, int out_size, void* d_ws, size_t ws_size,
                              hipStream_t stream) {
    const float* x     = (const float*)d_in[0];
    const int*   ei    = (const int*)d_in[1];
    const int*   batch = (const int*)d_in[2];
    const float* bn0g = (const float*)d_in[3];
    const float* bn0b = (const float*)d_in[4];
    const float* bn1g = (const float*)d_in[5];
    const float* bn1b = (const float*)d_in[6];
    const float* bn2g = (const float*)d_in[7];
    const float* bn2b = (const float*)d_in[8];
    const float* W1  = (const float*)d_in[9];
    const float* b1  = (const float*)d_in[10];
    const float* W2  = (const float*)d_in[11];
    const float* b2  = (const float*)d_in[12];
    const float* W3  = (const float*)d_in[13];
    const float* b3  = (const float*)d_in[14];
    const float* Wl1 = (const float*)d_in[15];
    const float* bl1 = (const float*)d_in[16];
    const float* Wl2 = (const float*)d_in[17];
    const float* bl2 = (const float*)d_in[18];

    const int N = in_sizes[0] / 7;
    const int E = in_sizes[1] / 2;
    const int EN = E + N;
    const int G = out_size / 2;
    const int NB = (N + 255) / 256;

    // padded strides (multiples of 4)
    const int SP1 = 72, SP2 = 136, SP3 = 200;

    const int* src = ei;
    const int* dst = ei + E;

    char* w = (char*)d_ws;
    auto alloc = [&](size_t bytes) -> void* {
        void* p = (void*)w;
        w += ((bytes + 255) / 256) * 256;
        return p;
    };
    __half* bufH = (__half*)alloc((size_t)N * SP3 * sizeof(__half));  // GEMM out (fp16)
    float* bufB  = (float*)alloc((size_t)N * SP3 * sizeof(float));    // aggregate out (fp32)
    float* disq  = (float*)alloc((size_t)N * sizeof(float));
    int*   deg   = (int*)  alloc((size_t)N * sizeof(int));
    int*   rs    = (int*)  alloc((size_t)N * sizeof(int));
    int*   cur   = (int*)  alloc((size_t)N * sizeof(int));
    int*   csr_s = (int*)  alloc((size_t)EN * sizeof(int));
    float* csr_w = (float*)alloc((size_t)EN * sizeof(float));
    float* colsum= (float*)alloc(256 * sizeof(float));
    float* colsq = (float*)alloc(256 * sizeof(float));
    float* scale = (float*)alloc(256 * sizeof(float));
    float* shift = (float*)alloc(256 * sizeof(float));
    float* pooled= (float*)alloc((size_t)G * 199 * sizeof(float));
    int*   gstart= (int*)  alloc((size_t)G * sizeof(int));
    int*   gend  = (int*)  alloc((size_t)G * sizeof(int));
    int*   bsum  = (int*)  alloc((size_t)NB * sizeof(int));
    int*   boff  = (int*)  alloc((size_t)NB * sizeof(int));

    // ---- degree + CSR (built once, reused by all 3 layers) ----
    k_init_deg<<<(N + 255) / 256, 256, 0, stream>>>(deg, N);
    k_count<<<(E + 255) / 256, 256, 0, stream>>>(dst, E, deg);
    k_disqrt<<<(N + 255) / 256, 256, 0, stream>>>(deg, disq, N);
    k_scan1<<<NB, 256, 0, stream>>>(deg, N, rs, bsum);
    k_scan2<<<1, 1, 0, stream>>>(bsum, NB, boff);
    k_scan3<<<NB, 256, 0, stream>>>(deg, rs, boff, N, rs, cur);
    k_fill<<<(EN + 255) / 256, 256, 0, stream>>>(src, dst, E, N, disq, cur, csr_s, csr_w);

    auto layer = [&](const float* Hin, int strideIn, const float* g, const float* b,
                     const float* Wm, const float* bias, float* Hout, int SPout,
                     int Cin, int Cout, int SPmid) {
        hipMemsetAsync(colsum, 0, Cin * sizeof(float), stream);
        hipMemsetAsync(colsq, 0, Cin * sizeof(float), stream);
        k_bnstats<<<NB, 256, 0, stream>>>(Hin, N, Cin, strideIn, colsum, colsq);
        k_bnfinal<<<1, 256, 0, stream>>>(colsum, colsq, g, b, Cin, 1.f / (float)N, scale, shift);
        dim3 grid((N + TM - 1) / TM, (Cout + TN - 1) / TN);
        k_gemm_bn<<<grid, 256, 0, stream>>>(Hin, strideIn, Wm, scale, shift, bufH, SPmid, N, Cin, Cout);
        k_aggregate_h<<<(N + 3) / 4, 256, 0, stream>>>(bufH, SPmid, rs, deg, csr_s, csr_w,
                                                       bias, Hout, SPout, N, Cout);
    };

    layer(x,    7,   bn0g, bn0b, W1, b1, bufB, SP1, 7,   71,  SP1);
    layer(bufB, SP1, bn1g, bn1b, W2, b2, bufB, SP2, 71,  135, SP2);
    layer(bufB, SP2, bn2g, bn2b, W3, b3, bufB, SP3, 135, 199, SP3);

    // ---- pool + head ----
    hipMemsetAsync(pooled, 0, (size_t)G * 199 * sizeof(float), stream);
    hipMemsetAsync(gstart, 0, G * sizeof(int), stream);
    hipMemsetAsync(gend, 0, G * sizeof(int), stream);
    k_pool<<<NB, 256, 0, stream>>>(bufB, SP3, batch, N, 199, pooled);
    k_bounds<<<(N + 255) / 256, 256, 0, stream>>>(batch, N, gstart, gend);
    k_mlp<<<G, 64, 0, stream>>>(pooled, gstart, gend, Wl1, bl1, Wl2, bl2, (float*)d_out, 199);
}

// Round 4
// 971.926 us; speedup vs baseline: 2.5753x; 1.1726x over previous
//
#include <hip/hip_runtime.h>
#include <hip/hip_fp16.h>

#define EPSV 1e-5f

// ---------------- degree / CSR construction ----------------

__global__ void k_init_deg(int* __restrict__ deg, int N) {
    int n = blockIdx.x * blockDim.x + threadIdx.x;
    if (n < N) deg[n] = 1;  // self loop
}

__global__ void k_count(const int* __restrict__ dst, int E, int* __restrict__ deg) {
    int e = blockIdx.x * blockDim.x + threadIdx.x;
    if (e < E) atomicAdd(&deg[dst[e]], 1);
}

__global__ void k_disqrt(const int* __restrict__ deg, float* __restrict__ disq, int N) {
    int n = blockIdx.x * blockDim.x + threadIdx.x;
    if (n < N) disq[n] = rsqrtf((float)deg[n]);
}

__global__ void k_scan1(const int* __restrict__ deg, int N,
                        int* __restrict__ incl, int* __restrict__ bsum) {
    __shared__ int s[256];
    int n = blockIdx.x * 256 + threadIdx.x;
    s[threadIdx.x] = (n < N) ? deg[n] : 0;
    __syncthreads();
    for (int off = 1; off < 256; off <<= 1) {
        int v = (threadIdx.x >= off) ? s[threadIdx.x - off] : 0;
        __syncthreads();
        s[threadIdx.x] += v;
        __syncthreads();
    }
    if (n < N) incl[n] = s[threadIdx.x];
    if (threadIdx.x == 255) bsum[blockIdx.x] = s[255];
}

__global__ void k_scan2(const int* __restrict__ bsum, int NB, int* __restrict__ boff) {
    if (blockIdx.x == 0 && threadIdx.x == 0) {
        int run = 0;
        for (int b = 0; b < NB; ++b) { boff[b] = run; run += bsum[b]; }
    }
}

__global__ void k_scan3(const int* __restrict__ deg, const int* __restrict__ incl,
                        const int* __restrict__ boff, int N,
                        int* __restrict__ rs, int* __restrict__ cur) {
    int n = blockIdx.x * 256 + threadIdx.x;
    if (n < N) {
        int v = incl[n] - deg[n] + boff[blockIdx.x];
        rs[n] = v;
        cur[n] = v;
    }
}

__global__ void k_fill(const int* __restrict__ src, const int* __restrict__ dst,
                       int E, int N, const float* __restrict__ disq,
                       int* __restrict__ cur, int* __restrict__ csr_s,
                       float* __restrict__ csr_w) {
    int i = blockIdx.x * blockDim.x + threadIdx.x;
    int total = E + N;
    if (i >= total) return;
    int s, d;
    if (i < E) { s = src[i]; d = dst[i]; }
    else       { s = i - E; d = s; }
    int slot = atomicAdd(&cur[d], 1);
    csr_s[slot] = s;
    csr_w[slot] = disq[s] * disq[d];
}

// rowsum of normalized adjacency S (graph-only, reused by all layers)
__global__ void k_rsum(const int* __restrict__ rs, const int* __restrict__ deg,
                       const float* __restrict__ csr_w, float* __restrict__ rsum, int N) {
    int n = blockIdx.x * blockDim.x + threadIdx.x;
    if (n >= N) return;
    int e0 = rs[n], eend = e0 + deg[n];
    float r = 0.f;
    for (int e = e0; e < eend; ++e) r += csr_w[e];
    rsum[n] = r;
}

// ---------------- BN stats for layer 0 input x (width 7) ----------------

__global__ void k_bnstats(const float* __restrict__ H, int N, int C, int SP,
                          float* __restrict__ colsum, float* __restrict__ colsq) {
    int j = threadIdx.x;
    if (j >= C) return;
    int r0 = blockIdx.x * 256;
    int rend = r0 + 256; if (rend > N) rend = N;
    float s = 0.f, q = 0.f;
    for (int r = r0; r < rend; ++r) {
        float v = H[(size_t)r * SP + j];
        s += v;
        q += v * v;
    }
    atomicAdd(&colsum[j], s);
    atomicAdd(&colsq[j], q);
}

__global__ void k_bnfinal(const float* __restrict__ colsum, const float* __restrict__ colsq,
                          const float* __restrict__ g, const float* __restrict__ b,
                          int C, float invN,
                          float* __restrict__ scale, float* __restrict__ shift) {
    int i = threadIdx.x;
    if (i < C) {
        float m = colsum[i] * invN;
        float v = colsq[i] * invN - m * m;
        float rstd = rsqrtf(fmaxf(v, 0.f) + EPSV);
        float sc = rstd * g[i];
        scale[i] = sc;
        shift[i] = b[i] - m * sc;
    }
}

// ---------------- pad x [N,7] -> xp [N,8] fp32 ----------------

__global__ void k_padx(const float* __restrict__ x, float* __restrict__ xp, int N) {
    int n = blockIdx.x * blockDim.x + threadIdx.x;
    if (n >= N) return;
    float4 a, b;
    a.x = x[(size_t)n * 7 + 0]; a.y = x[(size_t)n * 7 + 1];
    a.z = x[(size_t)n * 7 + 2]; a.w = x[(size_t)n * 7 + 3];
    b.x = x[(size_t)n * 7 + 4]; b.y = x[(size_t)n * 7 + 5];
    b.z = x[(size_t)n * 7 + 6]; b.w = 0.f;
    *(float4*)(xp + (size_t)n * 8) = a;
    *(float4*)(xp + (size_t)n * 8 + 4) = b;
}

// ---------------- gathers: G = S . X (pre-BN, pre-GEMM) ----------------

// width-8 fp32 input, one thread per node, fp16 output [N,8]
__global__ void k_gather8(const float* __restrict__ xp,
                          const int* __restrict__ rs, const int* __restrict__ deg,
                          const int* __restrict__ csr_s, const float* __restrict__ csr_w,
                          __half* __restrict__ out, int N) {
    int n = blockIdx.x * blockDim.x + threadIdx.x;
    if (n >= N) return;
    int e0 = rs[n], eend = e0 + deg[n];
    float a0 = 0.f, a1 = 0.f, a2 = 0.f, a3 = 0.f, a4 = 0.f, a5 = 0.f, a6 = 0.f, a7 = 0.f;
    for (int e = e0; e < eend; ++e) {
        int s = csr_s[e]; float w = csr_w[e];
        float4 r0 = *(const float4*)(xp + (size_t)s * 8);
        float4 r1 = *(const float4*)(xp + (size_t)s * 8 + 4);
        a0 = fmaf(w, r0.x, a0); a1 = fmaf(w, r0.y, a1);
        a2 = fmaf(w, r0.z, a2); a3 = fmaf(w, r0.w, a3);
        a4 = fmaf(w, r1.x, a4); a5 = fmaf(w, r1.y, a5);
        a6 = fmaf(w, r1.z, a6); a7 = fmaf(w, r1.w, a7);
    }
    __half h[8];
    h[0] = __float2half(a0); h[1] = __float2half(a1);
    h[2] = __float2half(a2); h[3] = __float2half(a3);
    h[4] = __float2half(a4); h[5] = __float2half(a5);
    h[6] = __float2half(a6); h[7] = __float2half(a7);
    *(float4*)(out + (size_t)n * 8) = *(float4*)h;
}

// generic fp16 gather; npw nodes per wave (1 or 2), 4 halfs per lane
__global__ __launch_bounds__(256) void k_gather_h(
    const __half* __restrict__ A, int SPh, int CH,
    const int* __restrict__ rs, const int* __restrict__ deg,
    const int* __restrict__ csr_s, const float* __restrict__ csr_w,
    __half* __restrict__ out, int N, int npw) {
    int wave = threadIdx.x >> 6;
    int lane = threadIdx.x & 63;
    int sub, lsub;
    if (npw == 2) { sub = lane >> 5; lsub = lane & 31; }
    else          { sub = 0;         lsub = lane; }
    int n = (blockIdx.x * 4 + wave) * npw + sub;
    if (n >= N) return;
    int c0 = lsub * 4;
    bool active = lsub < CH;
    int cc = active ? c0 : 0;

    int e0 = rs[n];
    int eend = e0 + deg[n];
    float acc0 = 0.f, acc1 = 0.f, acc2 = 0.f, acc3 = 0.f;

    int e = e0;
    for (; e + 4 <= eend; e += 4) {
        int s0 = csr_s[e + 0], s1 = csr_s[e + 1], s2 = csr_s[e + 2], s3 = csr_s[e + 3];
        float w0 = csr_w[e + 0], w1 = csr_w[e + 1], w2 = csr_w[e + 2], w3 = csr_w[e + 3];
        float2 r0 = *(const float2*)(A + (size_t)s0 * SPh + cc);
        float2 r1 = *(const float2*)(A + (size_t)s1 * SPh + cc);
        float2 r2 = *(const float2*)(A + (size_t)s2 * SPh + cc);
        float2 r3 = *(const float2*)(A + (size_t)s3 * SPh + cc);
        {
            float2 f01 = __half22float2(((const __half2*)&r0)[0]);
            float2 f23 = __half22float2(((const __half2*)&r0)[1]);
            acc0 = fmaf(w0, f01.x, acc0); acc1 = fmaf(w0, f01.y, acc1);
            acc2 = fmaf(w0, f23.x, acc2); acc3 = fmaf(w0, f23.y, acc3);
        }
        {
            float2 f01 = __half22float2(((const __half2*)&r1)[0]);
            float2 f23 = __half22float2(((const __half2*)&r1)[1]);
            acc0 = fmaf(w1, f01.x, acc0); acc1 = fmaf(w1, f01.y, acc1);
            acc2 = fmaf(w1, f23.x, acc2); acc3 = fmaf(w1, f23.y, acc3);
        }
        {
            float2 f01 = __half22float2(((const __half2*)&r2)[0]);
            float2 f23 = __half22float2(((const __half2*)&r2)[1]);
            acc0 = fmaf(w2, f01.x, acc0); acc1 = fmaf(w2, f01.y, acc1);
            acc2 = fmaf(w2, f23.x, acc2); acc3 = fmaf(w2, f23.y, acc3);
        }
        {
            float2 f01 = __half22float2(((const __half2*)&r3)[0]);
            float2 f23 = __half22float2(((const __half2*)&r3)[1]);
            acc0 = fmaf(w3, f01.x, acc0); acc1 = fmaf(w3, f01.y, acc1);
            acc2 = fmaf(w3, f23.x, acc2); acc3 = fmaf(w3, f23.y, acc3);
        }
    }
    for (; e < eend; ++e) {
        int s = csr_s[e];
        float w = csr_w[e];
        float2 r = *(const float2*)(A + (size_t)s * SPh + cc);
        float2 f01 = __half22float2(((const __half2*)&r)[0]);
        float2 f23 = __half22float2(((const __half2*)&r)[1]);
        acc0 = fmaf(w, f01.x, acc0); acc1 = fmaf(w, f01.y, acc1);
        acc2 = fmaf(w, f23.x, acc2); acc3 = fmaf(w, f23.y, acc3);
    }

    if (active) {
        __half2 h01 = __floats2half2_rn(acc0, acc1);
        __half2 h23 = __floats2half2_rn(acc2, acc3);
        float2 packed;
        ((__half2*)&packed)[0] = h01;
        ((__half2*)&packed)[1] = h23;
        *(float2*)(out + (size_t)n * SPh + c0) = packed;
    }
}

// ------- GEMM: H = relu((G*sc + rsum (x) sh) @ W + bias), fp16 in/out -------
// Optionally accumulates next layer's BN stats (on exact fp32 relu values).

#define TM 64
#define TN 64
#define TK 16

__global__ __launch_bounds__(256) void k_gemm_bn_h(
    const __half* __restrict__ A, int SPa,
    const float* __restrict__ W,
    const float* __restrict__ scale, const float* __restrict__ shift,
    const float* __restrict__ rsum, const float* __restrict__ bias,
    __half* __restrict__ out, int SPo,
    float* __restrict__ colsum, float* __restrict__ colsq, int do_stats,
    int N, int Cin, int Cout) {
    __shared__ float As[TK][TM + 4];
    __shared__ float Bs[TK][TN];
    __shared__ float s_sum[TN];
    __shared__ float s_sq[TN];
    const int r0 = blockIdx.x * TM;
    const int c0 = blockIdx.y * TN;
    const int t = threadIdx.x;
    const int tx = t & 15;
    const int ty = t >> 4;
    float acc[4][4] = {};
    if (t < TN) { s_sum[t] = 0.f; s_sq[t] = 0.f; }

    const int KT = (Cin + TK - 1) / TK;
    for (int kt = 0; kt < KT; ++kt) {
        int k0 = kt * TK;
        {
            int col = t & 15;
            int rbase = t >> 4;
            int gk = k0 + col;
            float sc = 0.f, sh = 0.f;
            if (gk < Cin) { sc = scale[gk]; sh = shift[gk]; }
#pragma unroll
            for (int i = 0; i < 4; ++i) {
                int row = rbase + i * 16;
                int gr = r0 + row;
                float v = 0.f;
                if (gr < N && gk < Cin)
                    v = __half2float(A[(size_t)gr * SPa + gk]) * sc + rsum[gr] * sh;
                As[col][row] = v;
            }
        }
        {
            int col = t & 63;
            int kb  = t >> 6;
#pragma unroll
            for (int i = 0; i < 4; ++i) {
                int k = kb + i * 4;
                int gk = k0 + k;
                int gc = c0 + col;
                float v = 0.f;
                if (gk < Cin && gc < Cout)
                    v = W[(size_t)gk * Cout + gc];
                Bs[k][col] = v;
            }
        }
        __syncthreads();
#pragma unroll
        for (int k = 0; k < TK; ++k) {
            float4 a = *(const float4*)&As[k][ty * 4];
            float4 b = *(const float4*)&Bs[k][tx * 4];
            float av[4] = {a.x, a.y, a.z, a.w};
            float bv[4] = {b.x, b.y, b.z, b.w};
#pragma unroll
            for (int i = 0; i < 4; ++i)
#pragma unroll
                for (int j = 0; j < 4; ++j)
                    acc[i][j] = fmaf(av[i], bv[j], acc[i][j]);
        }
        __syncthreads();
    }

    float bv[4];
#pragma unroll
    for (int j = 0; j < 4; ++j) {
        int gc = c0 + tx * 4 + j;
        bv[j] = (gc < Cout) ? bias[gc] : 0.f;
    }
    float ps[4] = {}, pq[4] = {};
#pragma unroll
    for (int i = 0; i < 4; ++i) {
        int gr = r0 + ty * 4 + i;
        if (gr >= N) continue;
        __half h4[4];
#pragma unroll
        for (int j = 0; j < 4; ++j) {
            float o = fmaxf(acc[i][j] + bv[j], 0.f);
            ps[j] += o;
            pq[j] += o * o;
            h4[j] = __float2half(o);
        }
        int gc = c0 + tx * 4;
        if (gc + 4 <= SPo) *(float2*)(out + (size_t)gr * SPo + gc) = *(float2*)h4;
    }
    if (do_stats) {
#pragma unroll
        for (int j = 0; j < 4; ++j) {
            atomicAdd(&s_sum[tx * 4 + j], ps[j]);
            atomicAdd(&s_sq[tx * 4 + j], pq[j]);
        }
        __syncthreads();
        if (t < TN) {
            atomicAdd(&colsum[c0 + t], s_sum[t]);
            atomicAdd(&colsq[c0 + t], s_sq[t]);
        }
    }
}

// ---------------- mean pool (fp16 input, batch is sorted) ----------------

__global__ void k_pool_h(const __half* __restrict__ H, int SP, const int* __restrict__ batch,
                         int N, int C, float* __restrict__ pooled) {
    __shared__ int sb[256];
    int r0 = blockIdx.x * 256;
    int rows = N - r0; if (rows > 256) rows = 256;
    if (threadIdx.x < rows) sb[threadIdx.x] = batch[r0 + threadIdx.x];
    __syncthreads();
    int c = threadIdx.x;
    if (c >= C) return;
    int cg = sb[0];
    float acc = 0.f;
    for (int r = 0; r < rows; ++r) {
        int g = sb[r];
        if (g != cg) { atomicAdd(&pooled[cg * C + c], acc); acc = 0.f; cg = g; }
        acc += __half2float(H[(size_t)(r0 + r) * SP + c]);
    }
    atomicAdd(&pooled[cg * C + c], acc);
}

__global__ void k_bounds(const int* __restrict__ batch, int N,
                         int* __restrict__ gstart, int* __restrict__ gend) {
    int n = blockIdx.x * blockDim.x + threadIdx.x;
    if (n >= N) return;
    int g = batch[n];
    if (n == 0 || batch[n - 1] != g) gstart[g] = n;
    if (n == N - 1 || batch[n + 1] != g) gend[g] = n + 1;
}

// ---------------- head MLP ----------------

__global__ void k_mlp(const float* __restrict__ pooled, const int* __restrict__ gstart,
                      const int* __restrict__ gend,
                      const float* __restrict__ Wl1, const float* __restrict__ bl1,
                      const float* __restrict__ Wl2, const float* __restrict__ bl2,
                      float* __restrict__ out, int C) {
    __shared__ float p[199];
    __shared__ float t1[49];
    int g = blockIdx.x;
    int cnt = gend[g] - gstart[g];
    float inv = 1.f / (float)(cnt > 1 ? cnt : 1);
    for (int k = threadIdx.x; k < C; k += blockDim.x) p[k] = pooled[g * C + k] * inv;
    __syncthreads();
    if (threadIdx.x < 49) {
        float acc = bl1[threadIdx.x];
        for (int k = 0; k < C; ++k) acc += p[k] * Wl1[k * 49 + threadIdx.x];
        t1[threadIdx.x] = acc;
    }
    __syncthreads();
    if (threadIdx.x < 2) {
        float acc = bl2[threadIdx.x];
        for (int k = 0; k < 49; ++k) acc += t1[k] * Wl2[k * 2 + threadIdx.x];
        out[g * 2 + threadIdx.x] = acc;
    }
}

// ---------------- launch ----------------

extern "C" void kernel_launch(void* const* d_in, const int* in_sizes, int n_in,
                              void* d_out, int out_size, void* d_ws, size_t ws_size,
                              hipStream_t stream) {
    const float* x     = (const float*)d_in[0];
    const int*   ei    = (const int*)d_in[1];
    const int*   batch = (const int*)d_in[2];
    const float* bn0g = (const float*)d_in[3];
    const float* bn0b = (const float*)d_in[4];
    const float* bn1g = (const float*)d_in[5];
    const float* bn1b = (const float*)d_in[6];
    const float* bn2g = (const float*)d_in[7];
    const float* bn2b = (const float*)d_in[8];
    const float* W1  = (const float*)d_in[9];
    const float* b1  = (const float*)d_in[10];
    const float* W2  = (const float*)d_in[11];
    const float* b2  = (const float*)d_in[12];
    const float* W3  = (const float*)d_in[13];
    const float* b3  = (const float*)d_in[14];
    const float* Wl1 = (const float*)d_in[15];
    const float* bl1 = (const float*)d_in[16];
    const float* Wl2 = (const float*)d_in[17];
    const float* bl2 = (const float*)d_in[18];

    const int N = in_sizes[0] / 7;
    const int E = in_sizes[1] / 2;
    const int EN = E + N;
    const int G = out_size / 2;
    const int NB = (N + 255) / 256;

    const int SP1 = 72, SP2 = 136, SP3 = 200;  // padded half-strides of H1/H2/H3

    const int* src = ei;
    const int* dst = ei + E;

    char* w = (char*)d_ws;
    auto alloc = [&](size_t bytes) -> void* {
        void* p = (void*)w;
        w += ((bytes + 255) / 256) * 256;
        return p;
    };
    __half* bufH = (__half*)alloc((size_t)N * SP3 * sizeof(__half));  // H buffers
    __half* bufG = (__half*)alloc((size_t)N * SP2 * sizeof(__half));  // G buffers
    float* xp    = (float*)alloc((size_t)N * 8 * sizeof(float));
    float* disq  = (float*)alloc((size_t)N * sizeof(float));
    float* rsum  = (float*)alloc((size_t)N * sizeof(float));
    int*   deg   = (int*)  alloc((size_t)N * sizeof(int));
    int*   rs    = (int*)  alloc((size_t)N * sizeof(int));
    int*   cur   = (int*)  alloc((size_t)N * sizeof(int));
    int*   csr_s = (int*)  alloc((size_t)EN * sizeof(int));
    float* csr_w = (float*)alloc((size_t)EN * sizeof(float));
    float* colsum0 = (float*)alloc(256 * sizeof(float));
    float* colsq0  = (float*)alloc(256 * sizeof(float));
    float* colsumA = (float*)alloc(256 * sizeof(float));
    float* colsqA  = (float*)alloc(256 * sizeof(float));
    float* colsumB = (float*)alloc(256 * sizeof(float));
    float* colsqB  = (float*)alloc(256 * sizeof(float));
    float* scale = (float*)alloc(256 * sizeof(float));
    float* shift = (float*)alloc(256 * sizeof(float));
    float* pooled= (float*)alloc((size_t)G * 199 * sizeof(float));
    int*   gstart= (int*)  alloc((size_t)G * sizeof(int));
    int*   gend  = (int*)  alloc((size_t)G * sizeof(int));
    int*   bsum  = (int*)  alloc((size_t)NB * sizeof(int));
    int*   boff  = (int*)  alloc((size_t)NB * sizeof(int));

    // zero all stat accumulators + pool buffers
    hipMemsetAsync(colsum0, 0, 6 * 256 * sizeof(float) + 2 * 256 * sizeof(float), stream);
    hipMemsetAsync(pooled, 0, (size_t)G * 199 * sizeof(float), stream);
    hipMemsetAsync(gstart, 0, G * sizeof(int), stream);
    hipMemsetAsync(gend, 0, G * sizeof(int), stream);

    // ---- degree + CSR + rowsum ----
    k_init_deg<<<(N + 255) / 256, 256, 0, stream>>>(deg, N);
    k_count<<<(E + 255) / 256, 256, 0, stream>>>(dst, E, deg);
    k_disqrt<<<(N + 255) / 256, 256, 0, stream>>>(deg, disq, N);
    k_scan1<<<NB, 256, 0, stream>>>(deg, N, rs, bsum);
    k_scan2<<<1, 1, 0, stream>>>(bsum, NB, boff);
    k_scan3<<<NB, 256, 0, stream>>>(deg, rs, boff, N, rs, cur);
    k_fill<<<(EN + 255) / 256, 256, 0, stream>>>(src, dst, E, N, disq, cur, csr_s, csr_w);
    k_rsum<<<(N + 255) / 256, 256, 0, stream>>>(rs, deg, csr_w, rsum, N);

    // ---- layer 1: stats(x), G0 = S.x, H1 = relu(aff(G0) @ W1 + b1) ----
    k_bnstats<<<NB, 256, 0, stream>>>(x, N, 7, 7, colsum0, colsq0);
    k_bnfinal<<<1, 256, 0, stream>>>(colsum0, colsq0, bn0g, bn0b, 7, 1.f / (float)N, scale, shift);
    k_padx<<<(N + 255) / 256, 256, 0, stream>>>(x, xp, N);
    k_gather8<<<(N + 255) / 256, 256, 0, stream>>>(xp, rs, deg, csr_s, csr_w, bufG, N);
    {
        dim3 grid((N + TM - 1) / TM, (71 + TN - 1) / TN);
        k_gemm_bn_h<<<grid, 256, 0, stream>>>(bufG, 8, W1, scale, shift, rsum, b1,
                                              bufH, SP1, colsumA, colsqA, 1, N, 7, 71);
    }
    // ---- layer 2 ----
    k_bnfinal<<<1, 256, 0, stream>>>(colsumA, colsqA, bn1g, bn1b, 71, 1.f / (float)N, scale, shift);
    k_gather_h<<<(N + 7) / 8, 256, 0, stream>>>(bufH, SP1, 18, rs, deg, csr_s, csr_w, bufG, N, 2);
    {
        dim3 grid((N + TM - 1) / TM, (135 + TN - 1) / TN);
        k_gemm_bn_h<<<grid, 256, 0, stream>>>(bufG, SP1, W2, scale, shift, rsum, b2,
                                              bufH, SP2, colsumB, colsqB, 1, N, 71, 135);
    }
    // ---- layer 3 ----
    k_bnfinal<<<1, 256, 0, stream>>>(colsumB, colsqB, bn2g, bn2b, 135, 1.f / (float)N, scale, shift);
    k_gather_h<<<(N + 3) / 4, 256, 0, stream>>>(bufH, SP2, 34, rs, deg, csr_s, csr_w, bufG, N, 1);
    {
        dim3 grid((N + TM - 1) / TM, (199 + TN - 1) / TN);
        k_gemm_bn_h<<<grid, 256, 0, stream>>>(bufG, SP2, W3, scale, shift, rsum, b3,
                                              bufH, SP3, colsumB, colsqB, 0, N, 135, 199);
    }

    // ---- pool + head ----
    k_pool_h<<<NB, 256, 0, stream>>>(bufH, SP3, batch, N, 199, pooled);
    k_bounds<<<(N + 255) / 256, 256, 0, stream>>>(batch, N, gstart, gend);
    k_mlp<<<G, 64, 0, stream>>>(pooled, gstart, gend, Wl1, bl1, Wl2, bl2, (float*)d_out, 199);
}

// Round 5
// 808.448 us; speedup vs baseline: 3.0961x; 1.2022x over previous
//
#include <hip/hip_runtime.h>
#include <hip/hip_fp16.h>

#define EPSV 1e-5f

typedef _Float16 f16;
typedef f16 half8 __attribute__((ext_vector_type(8)));
typedef float f32x4 __attribute__((ext_vector_type(4)));

// ---------------- degree / CSR construction ----------------

__global__ void k_init_deg(int* __restrict__ deg, int N) {
    int n = blockIdx.x * blockDim.x + threadIdx.x;
    if (n < N) deg[n] = 1;  // self loop
}

__global__ void k_count(const int* __restrict__ dst, int E, int* __restrict__ deg) {
    int e = blockIdx.x * blockDim.x + threadIdx.x;
    if (e < E) atomicAdd(&deg[dst[e]], 1);
}

__global__ void k_disqrt(const int* __restrict__ deg, float* __restrict__ disq, int N) {
    int n = blockIdx.x * blockDim.x + threadIdx.x;
    if (n < N) disq[n] = rsqrtf((float)deg[n]);
}

__global__ void k_scan1(const int* __restrict__ deg, int N,
                        int* __restrict__ incl, int* __restrict__ bsum) {
    __shared__ int s[256];
    int n = blockIdx.x * 256 + threadIdx.x;
    s[threadIdx.x] = (n < N) ? deg[n] : 0;
    __syncthreads();
    for (int off = 1; off < 256; off <<= 1) {
        int v = (threadIdx.x >= off) ? s[threadIdx.x - off] : 0;
        __syncthreads();
        s[threadIdx.x] += v;
        __syncthreads();
    }
    if (n < N) incl[n] = s[threadIdx.x];
    if (threadIdx.x == 255) bsum[blockIdx.x] = s[255];
}

__global__ void k_scan2(const int* __restrict__ bsum, int NB, int* __restrict__ boff) {
    if (blockIdx.x == 0 && threadIdx.x == 0) {
        int run = 0;
        for (int b = 0; b < NB; ++b) { boff[b] = run; run += bsum[b]; }
    }
}

__global__ void k_scan3(const int* __restrict__ deg, const int* __restrict__ incl,
                        const int* __restrict__ boff, int N,
                        int* __restrict__ rs, int* __restrict__ cur) {
    int n = blockIdx.x * 256 + threadIdx.x;
    if (n < N) {
        int v = incl[n] - deg[n] + boff[blockIdx.x];
        rs[n] = v;
        cur[n] = v;
    }
}

__global__ void k_fill(const int* __restrict__ src, const int* __restrict__ dst,
                       int E, int N, const float* __restrict__ disq,
                       int* __restrict__ cur, int* __restrict__ csr_s,
                       float* __restrict__ csr_w) {
    int i = blockIdx.x * blockDim.x + threadIdx.x;
    int total = E + N;
    if (i >= total) return;
    int s, d;
    if (i < E) { s = src[i]; d = dst[i]; }
    else       { s = i - E; d = s; }
    int slot = atomicAdd(&cur[d], 1);
    csr_s[slot] = s;
    csr_w[slot] = disq[s] * disq[d];
}

__global__ void k_rsum(const int* __restrict__ rs, const int* __restrict__ deg,
                       const float* __restrict__ csr_w, float* __restrict__ rsum, int N) {
    int n = blockIdx.x * blockDim.x + threadIdx.x;
    if (n >= N) return;
    int e0 = rs[n], eend = e0 + deg[n];
    float r = 0.f;
    for (int e = e0; e < eend; ++e) r += csr_w[e];
    rsum[n] = r;
}

// ---------------- BN stats for layer 0 input x (width 7) ----------------

__global__ void k_bnstats(const float* __restrict__ H, int N, int C, int SP,
                          float* __restrict__ colsum, float* __restrict__ colsq) {
    int j = threadIdx.x;
    if (j >= C) return;
    int r0 = blockIdx.x * 256;
    int rend = r0 + 256; if (rend > N) rend = N;
    float s = 0.f, q = 0.f;
    for (int r = r0; r < rend; ++r) {
        float v = H[(size_t)r * SP + j];
        s += v;
        q += v * v;
    }
    atomicAdd(&colsum[j], s);
    atomicAdd(&colsq[j], q);
}

__global__ void k_bnfinal(const float* __restrict__ colsum, const float* __restrict__ colsq,
                          const float* __restrict__ g, const float* __restrict__ b,
                          int C, float invN,
                          float* __restrict__ scale, float* __restrict__ shift) {
    int i = threadIdx.x;
    if (i < C) {
        float m = colsum[i] * invN;
        float v = colsq[i] * invN - m * m;
        float rstd = rsqrtf(fmaxf(v, 0.f) + EPSV);
        float sc = rstd * g[i];
        scale[i] = sc;
        shift[i] = b[i] - m * sc;
    }
}

// ---- per-layer weight prep: Wp_t[n][k] = fp16(scale[k] * W[k][n]), zero-padded ----

__global__ void k_prepw(const float* __restrict__ W, const float* __restrict__ scale,
                        f16* __restrict__ Wp, int Cin, int Cout, int KP, int NP) {
    int idx = blockIdx.x * blockDim.x + threadIdx.x;
    if (idx >= NP * KP) return;
    int n = idx / KP;
    int k = idx - n * KP;
    float v = 0.f;
    if (k < Cin && n < Cout) v = scale[k] * W[(size_t)k * Cout + n];
    Wp[idx] = (f16)v;
}

// wrow[c] = sum_k shift[k] * W[k][c]  (0 for pad cols)
__global__ void k_wrow(const float* __restrict__ W, const float* __restrict__ shift,
                       float* __restrict__ wrow, int Cin, int Cout, int NP) {
    int c = blockIdx.x * blockDim.x + threadIdx.x;
    if (c >= NP) return;
    float acc = 0.f;
    if (c < Cout)
        for (int k = 0; k < Cin; ++k) acc += shift[k] * W[(size_t)k * Cout + c];
    wrow[c] = acc;
}

// ---------------- pad x [N,7] -> xp [N,8] fp32 ----------------

__global__ void k_padx(const float* __restrict__ x, float* __restrict__ xp, int N) {
    int n = blockIdx.x * blockDim.x + threadIdx.x;
    if (n >= N) return;
    float4 a, b;
    a.x = x[(size_t)n * 7 + 0]; a.y = x[(size_t)n * 7 + 1];
    a.z = x[(size_t)n * 7 + 2]; a.w = x[(size_t)n * 7 + 3];
    b.x = x[(size_t)n * 7 + 4]; b.y = x[(size_t)n * 7 + 5];
    b.z = x[(size_t)n * 7 + 6]; b.w = 0.f;
    *(float4*)(xp + (size_t)n * 8) = a;
    *(float4*)(xp + (size_t)n * 8 + 4) = b;
}

// ---------------- gathers: G = S . X ----------------

__global__ void k_gather8(const float* __restrict__ xp,
                          const int* __restrict__ rs, const int* __restrict__ deg,
                          const int* __restrict__ csr_s, const float* __restrict__ csr_w,
                          __half* __restrict__ out, int N) {
    int n = blockIdx.x * blockDim.x + threadIdx.x;
    if (n >= N) return;
    int e0 = rs[n], eend = e0 + deg[n];
    float a0 = 0.f, a1 = 0.f, a2 = 0.f, a3 = 0.f, a4 = 0.f, a5 = 0.f, a6 = 0.f, a7 = 0.f;
    for (int e = e0; e < eend; ++e) {
        int s = csr_s[e]; float w = csr_w[e];
        float4 r0 = *(const float4*)(xp + (size_t)s * 8);
        float4 r1 = *(const float4*)(xp + (size_t)s * 8 + 4);
        a0 = fmaf(w, r0.x, a0); a1 = fmaf(w, r0.y, a1);
        a2 = fmaf(w, r0.z, a2); a3 = fmaf(w, r0.w, a3);
        a4 = fmaf(w, r1.x, a4); a5 = fmaf(w, r1.y, a5);
        a6 = fmaf(w, r1.z, a6); a7 = fmaf(w, r1.w, a7);
    }
    __half h[8];
    h[0] = __float2half(a0); h[1] = __float2half(a1);
    h[2] = __float2half(a2); h[3] = __float2half(a3);
    h[4] = __float2half(a4); h[5] = __float2half(a5);
    h[6] = __float2half(a6); h[7] = __float2half(a7);
    *(float4*)(out + (size_t)n * 8) = *(float4*)h;
}

__global__ __launch_bounds__(256) void k_gather_h(
    const __half* __restrict__ A, int SPh, int CH,
    const int* __restrict__ rs, const int* __restrict__ deg,
    const int* __restrict__ csr_s, const float* __restrict__ csr_w,
    __half* __restrict__ out, int N, int npw) {
    int wave = threadIdx.x >> 6;
    int lane = threadIdx.x & 63;
    int sub, lsub;
    if (npw == 2) { sub = lane >> 5; lsub = lane & 31; }
    else          { sub = 0;         lsub = lane; }
    int n = (blockIdx.x * 4 + wave) * npw + sub;
    if (n >= N) return;
    int c0 = lsub * 4;
    bool active = lsub < CH;
    int cc = active ? c0 : 0;

    int e0 = rs[n];
    int eend = e0 + deg[n];
    float acc0 = 0.f, acc1 = 0.f, acc2 = 0.f, acc3 = 0.f;

    int e = e0;
    for (; e + 4 <= eend; e += 4) {
        int s0 = csr_s[e + 0], s1 = csr_s[e + 1], s2 = csr_s[e + 2], s3 = csr_s[e + 3];
        float w0 = csr_w[e + 0], w1 = csr_w[e + 1], w2 = csr_w[e + 2], w3 = csr_w[e + 3];
        float2 r0 = *(const float2*)(A + (size_t)s0 * SPh + cc);
        float2 r1 = *(const float2*)(A + (size_t)s1 * SPh + cc);
        float2 r2 = *(const float2*)(A + (size_t)s2 * SPh + cc);
        float2 r3 = *(const float2*)(A + (size_t)s3 * SPh + cc);
        {
            float2 f01 = __half22float2(((const __half2*)&r0)[0]);
            float2 f23 = __half22float2(((const __half2*)&r0)[1]);
            acc0 = fmaf(w0, f01.x, acc0); acc1 = fmaf(w0, f01.y, acc1);
            acc2 = fmaf(w0, f23.x, acc2); acc3 = fmaf(w0, f23.y, acc3);
        }
        {
            float2 f01 = __half22float2(((const __half2*)&r1)[0]);
            float2 f23 = __half22float2(((const __half2*)&r1)[1]);
            acc0 = fmaf(w1, f01.x, acc0); acc1 = fmaf(w1, f01.y, acc1);
            acc2 = fmaf(w1, f23.x, acc2); acc3 = fmaf(w1, f23.y, acc3);
        }
        {
            float2 f01 = __half22float2(((const __half2*)&r2)[0]);
            float2 f23 = __half22float2(((const __half2*)&r2)[1]);
            acc0 = fmaf(w2, f01.x, acc0); acc1 = fmaf(w2, f01.y, acc1);
            acc2 = fmaf(w2, f23.x, acc2); acc3 = fmaf(w2, f23.y, acc3);
        }
        {
            float2 f01 = __half22float2(((const __half2*)&r3)[0]);
            float2 f23 = __half22float2(((const __half2*)&r3)[1]);
            acc0 = fmaf(w3, f01.x, acc0); acc1 = fmaf(w3, f01.y, acc1);
            acc2 = fmaf(w3, f23.x, acc2); acc3 = fmaf(w3, f23.y, acc3);
        }
    }
    for (; e < eend; ++e) {
        int s = csr_s[e];
        float w = csr_w[e];
        float2 r = *(const float2*)(A + (size_t)s * SPh + cc);
        float2 f01 = __half22float2(((const __half2*)&r)[0]);
        float2 f23 = __half22float2(((const __half2*)&r)[1]);
        acc0 = fmaf(w, f01.x, acc0); acc1 = fmaf(w, f01.y, acc1);
        acc2 = fmaf(w, f23.x, acc2); acc3 = fmaf(w, f23.y, acc3);
    }

    if (active) {
        __half2 h01 = __floats2half2_rn(acc0, acc1);
        __half2 h23 = __floats2half2_rn(acc2, acc3);
        float2 packed;
        ((__half2*)&packed)[0] = h01;
        ((__half2*)&packed)[1] = h23;
        *(float2*)(out + (size_t)n * SPh + c0) = packed;
    }
}

// ------------- MFMA GEMM: H = relu(G @ Wp_t^T + rsum (x) wrow + bias) -------------
// Block: 128 rows x 64 cols; 4 waves, wave = 32 rows x 64 cols.
// A: fp16 [N, SPa] staged in LDS; B: fp16 Wp_t [NP, KP] direct global b128 frags.
// Fuses next-layer BN stats. Pad cols (>= Cout) stored as exact 0.

__global__ __launch_bounds__(256) void k_gemm_mfma(
    const f16* __restrict__ A, int SPa,
    const f16* __restrict__ Bt, int KP,
    const float* __restrict__ rsum, const float* __restrict__ wrow,
    const float* __restrict__ bias,
    f16* __restrict__ out, int SPo,
    float* __restrict__ colsum, float* __restrict__ colsq, int do_stats,
    int N, int Cout) {
    __shared__ f16 As[128][40];         // stride 40 halfs = 80B: 2-way-free banks
    __shared__ float s_sum[64];
    __shared__ float s_sq[64];
    const int r0 = blockIdx.x * 128;
    const int c0 = blockIdx.y * 64;
    const int t = threadIdx.x;
    const int wave = t >> 6, lane = t & 63;
    const int l15 = lane & 15, quad = lane >> 4;

    if (t < 64) { s_sum[t] = 0.f; s_sq[t] = 0.f; }

    f32x4 zero4 = {0.f, 0.f, 0.f, 0.f};
    f32x4 acc[2][4];
#pragma unroll
    for (int mi = 0; mi < 2; ++mi)
#pragma unroll
        for (int ni = 0; ni < 4; ++ni) acc[mi][ni] = zero4;

    const int KT = KP >> 5;  // KP multiple of 32
    for (int kt = 0; kt < KT; ++kt) {
        int k0 = kt * 32;
        // stage A: 128 rows x 32 halfs; each thread 4x (4-half) loads
        {
            int kcol = (t & 7) * 4;
            int rbase = t >> 3;
            int gk = k0 + kcol;
            bool kok = (gk + 4 <= SPa);
#pragma unroll
            for (int i = 0; i < 4; ++i) {
                int row = rbase + i * 32;
                int gr = r0 + row;
                ushort4 v = {0, 0, 0, 0};
                if (gr < N && kok)
                    v = *(const ushort4*)(A + (size_t)gr * SPa + gk);
                *(ushort4*)&As[row][kcol] = v;
            }
        }
        __syncthreads();
        half8 a0 = *(const half8*)&As[wave * 32 + l15][quad * 8];
        half8 a1 = *(const half8*)&As[wave * 32 + 16 + l15][quad * 8];
#pragma unroll
        for (int ni = 0; ni < 4; ++ni) {
            half8 b = *(const half8*)(Bt + (size_t)(c0 + ni * 16 + l15) * KP + k0 + quad * 8);
            acc[0][ni] = __builtin_amdgcn_mfma_f32_16x16x32_f16(a0, b, acc[0][ni], 0, 0, 0);
            acc[1][ni] = __builtin_amdgcn_mfma_f32_16x16x32_f16(a1, b, acc[1][ni], 0, 0, 0);
        }
        __syncthreads();
    }

    // epilogue: D[row][col]: row = quad*4+reg (+tile), col = l15 (+tile)
    float wr[4], bi[4];
#pragma unroll
    for (int ni = 0; ni < 4; ++ni) {
        int gc = c0 + ni * 16 + l15;
        wr[ni] = wrow[gc];
        bi[ni] = (gc < Cout) ? bias[gc] : 0.f;
    }
    float ps[4] = {}, pq[4] = {};
#pragma unroll
    for (int mi = 0; mi < 2; ++mi) {
#pragma unroll
        for (int reg = 0; reg < 4; ++reg) {
            int gr = r0 + wave * 32 + mi * 16 + quad * 4 + reg;
            if (gr >= N) continue;
            float rsv = rsum[gr];
#pragma unroll
            for (int ni = 0; ni < 4; ++ni) {
                int gc = c0 + ni * 16 + l15;
                float o = acc[mi][ni][reg] + rsv * wr[ni] + bi[ni];
                o = fmaxf(o, 0.f);
                if (gc >= Cout) o = 0.f;     // pad cols exact zero
                ps[ni] += o; pq[ni] += o * o;
                if (gc < SPo) out[(size_t)gr * SPo + gc] = (f16)o;
            }
        }
    }
    if (do_stats) {
#pragma unroll
        for (int ni = 0; ni < 4; ++ni) {
            int cl = ni * 16 + l15;
            atomicAdd(&s_sum[cl], ps[ni]);
            atomicAdd(&s_sq[cl], pq[ni]);
        }
        __syncthreads();
        if (t < 64 && c0 + t < Cout) {
            atomicAdd(&colsum[c0 + t], s_sum[t]);
            atomicAdd(&colsq[c0 + t], s_sq[t]);
        }
    }
}

// ---------------- mean pool (fp16 input, batch is sorted) ----------------

__global__ void k_pool_h(const __half* __restrict__ H, int SP, const int* __restrict__ batch,
                         int N, int C, float* __restrict__ pooled) {
    __shared__ int sb[256];
    int r0 = blockIdx.x * 256;
    int rows = N - r0; if (rows > 256) rows = 256;
    if (threadIdx.x < rows) sb[threadIdx.x] = batch[r0 + threadIdx.x];
    __syncthreads();
    int c = threadIdx.x;
    if (c >= C) return;
    int cg = sb[0];
    float acc = 0.f;
    for (int r = 0; r < rows; ++r) {
        int g = sb[r];
        if (g != cg) { atomicAdd(&pooled[cg * C + c], acc); acc = 0.f; cg = g; }
        acc += __half2float(H[(size_t)(r0 + r) * SP + c]);
    }
    atomicAdd(&pooled[cg * C + c], acc);
}

__global__ void k_bounds(const int* __restrict__ batch, int N,
                         int* __restrict__ gstart, int* __restrict__ gend) {
    int n = blockIdx.x * blockDim.x + threadIdx.x;
    if (n >= N) return;
    int g = batch[n];
    if (n == 0 || batch[n - 1] != g) gstart[g] = n;
    if (n == N - 1 || batch[n + 1] != g) gend[g] = n + 1;
}

// ---------------- head MLP ----------------

__global__ void k_mlp(const float* __restrict__ pooled, const int* __restrict__ gstart,
                      const int* __restrict__ gend,
                      const float* __restrict__ Wl1, const float* __restrict__ bl1,
                      const float* __restrict__ Wl2, const float* __restrict__ bl2,
                      float* __restrict__ out, int C) {
    __shared__ float p[199];
    __shared__ float t1[49];
    int g = blockIdx.x;
    int cnt = gend[g] - gstart[g];
    float inv = 1.f / (float)(cnt > 1 ? cnt : 1);
    for (int k = threadIdx.x; k < C; k += blockDim.x) p[k] = pooled[g * C + k] * inv;
    __syncthreads();
    if (threadIdx.x < 49) {
        float acc = bl1[threadIdx.x];
        for (int k = 0; k < C; ++k) acc += p[k] * Wl1[k * 49 + threadIdx.x];
        t1[threadIdx.x] = acc;
    }
    __syncthreads();
    if (threadIdx.x < 2) {
        float acc = bl2[threadIdx.x];
        for (int k = 0; k < 49; ++k) acc += t1[k] * Wl2[k * 2 + threadIdx.x];
        out[g * 2 + threadIdx.x] = acc;
    }
}

// ---------------- launch ----------------

extern "C" void kernel_launch(void* const* d_in, const int* in_sizes, int n_in,
                              void* d_out, int out_size, void* d_ws, size_t ws_size,
                              hipStream_t stream) {
    const float* x     = (const float*)d_in[0];
    const int*   ei    = (const int*)d_in[1];
    const int*   batch = (const int*)d_in[2];
    const float* bn0g = (const float*)d_in[3];
    const float* bn0b = (const float*)d_in[4];
    const float* bn1g = (const float*)d_in[5];
    const float* bn1b = (const float*)d_in[6];
    const float* bn2g = (const float*)d_in[7];
    const float* bn2b = (const float*)d_in[8];
    const float* W1  = (const float*)d_in[9];
    const float* b1  = (const float*)d_in[10];
    const float* W2  = (const float*)d_in[11];
    const float* b2  = (const float*)d_in[12];
    const float* W3  = (const float*)d_in[13];
    const float* b3  = (const float*)d_in[14];
    const float* Wl1 = (const float*)d_in[15];
    const float* bl1 = (const float*)d_in[16];
    const float* Wl2 = (const float*)d_in[17];
    const float* bl2 = (const float*)d_in[18];

    const int N = in_sizes[0] / 7;
    const int E = in_sizes[1] / 2;
    const int EN = E + N;
    const int G = out_size / 2;
    const int NB = (N + 255) / 256;

    const int SP1 = 72, SP2 = 136, SP3 = 200;  // padded half-strides of H1/H2/H3

    const int* src = ei;
    const int* dst = ei + E;

    char* w = (char*)d_ws;
    auto alloc = [&](size_t bytes) -> void* {
        void* p = (void*)w;
        w += ((bytes + 255) / 256) * 256;
        return p;
    };
    __half* bufH = (__half*)alloc((size_t)N * SP3 * sizeof(__half));
    __half* bufG = (__half*)alloc((size_t)N * SP2 * sizeof(__half));
    f16*    wp   = (f16*)  alloc((size_t)256 * 160 * sizeof(f16));   // Wp_t [NP][KP]
    float*  wrow = (float*)alloc(256 * sizeof(float));
    float* xp    = (float*)alloc((size_t)N * 8 * sizeof(float));
    float* disq  = (float*)alloc((size_t)N * sizeof(float));
    float* rsum  = (float*)alloc((size_t)N * sizeof(float));
    int*   deg   = (int*)  alloc((size_t)N * sizeof(int));
    int*   rs    = (int*)  alloc((size_t)N * sizeof(int));
    int*   cur   = (int*)  alloc((size_t)N * sizeof(int));
    int*   csr_s = (int*)  alloc((size_t)EN * sizeof(int));
    float* csr_w = (float*)alloc((size_t)EN * sizeof(float));
    float* colsum0 = (float*)alloc(256 * sizeof(float));
    float* colsq0  = (float*)alloc(256 * sizeof(float));
    float* colsumA = (float*)alloc(256 * sizeof(float));
    float* colsqA  = (float*)alloc(256 * sizeof(float));
    float* colsumB = (float*)alloc(256 * sizeof(float));
    float* colsqB  = (float*)alloc(256 * sizeof(float));
    float* scale = (float*)alloc(256 * sizeof(float));
    float* shift = (float*)alloc(256 * sizeof(float));
    float* pooled= (float*)alloc((size_t)G * 199 * sizeof(float));
    int*   gstart= (int*)  alloc((size_t)G * sizeof(int));
    int*   gend  = (int*)  alloc((size_t)G * sizeof(int));
    int*   bsum  = (int*)  alloc((size_t)NB * sizeof(int));
    int*   boff  = (int*)  alloc((size_t)NB * sizeof(int));

    // zero stats accumulators (6 contiguous 1KB-aligned blocks) + pool bufs
    hipMemsetAsync(colsum0, 0, 6 * 256 * sizeof(float), stream);
    hipMemsetAsync(pooled, 0, (size_t)G * 199 * sizeof(float), stream);
    hipMemsetAsync(gstart, 0, G * sizeof(int), stream);
    hipMemsetAsync(gend, 0, G * sizeof(int), stream);

    // ---- degree + CSR + rowsum ----
    k_init_deg<<<(N + 255) / 256, 256, 0, stream>>>(deg, N);
    k_count<<<(E + 255) / 256, 256, 0, stream>>>(dst, E, deg);
    k_disqrt<<<(N + 255) / 256, 256, 0, stream>>>(deg, disq, N);
    k_scan1<<<NB, 256, 0, stream>>>(deg, N, rs, bsum);
    k_scan2<<<1, 1, 0, stream>>>(bsum, NB, boff);
    k_scan3<<<NB, 256, 0, stream>>>(deg, rs, boff, N, rs, cur);
    k_fill<<<(EN + 255) / 256, 256, 0, stream>>>(src, dst, E, N, disq, cur, csr_s, csr_w);
    k_rsum<<<(N + 255) / 256, 256, 0, stream>>>(rs, deg, csr_w, rsum, N);

    const int GB = (N + 127) / 128;  // mfma grid x

    // ---- layer 1: stats(x); G0 = S.x; H1 = relu(G0 @ W1' + rsum*wrow + b1) ----
    k_bnstats<<<NB, 256, 0, stream>>>(x, N, 7, 7, colsum0, colsq0);
    k_bnfinal<<<1, 256, 0, stream>>>(colsum0, colsq0, bn0g, bn0b, 7, 1.f / (float)N, scale, shift);
    k_prepw<<<(128 * 32 + 255) / 256, 256, 0, stream>>>(W1, scale, wp, 7, 71, 32, 128);
    k_wrow<<<1, 128, 0, stream>>>(W1, shift, wrow, 7, 71, 128);
    k_padx<<<(N + 255) / 256, 256, 0, stream>>>(x, xp, N);
    k_gather8<<<(N + 255) / 256, 256, 0, stream>>>(xp, rs, deg, csr_s, csr_w, bufG, N);
    {
        dim3 grid(GB, 2);
        k_gemm_mfma<<<grid, 256, 0, stream>>>((const f16*)bufG, 8, wp, 32, rsum, wrow, b1,
                                              (f16*)bufH, SP1, colsumA, colsqA, 1, N, 71);
    }
    // ---- layer 2 ----
    k_bnfinal<<<1, 256, 0, stream>>>(colsumA, colsqA, bn1g, bn1b, 71, 1.f / (float)N, scale, shift);
    k_prepw<<<(192 * 96 + 255) / 256, 256, 0, stream>>>(W2, scale, wp, 71, 135, 96, 192);
    k_wrow<<<1, 192, 0, stream>>>(W2, shift, wrow, 71, 135, 192);
    k_gather_h<<<(N + 7) / 8, 256, 0, stream>>>(bufH, SP1, 18, rs, deg, csr_s, csr_w, bufG, N, 2);
    {
        dim3 grid(GB, 3);
        k_gemm_mfma<<<grid, 256, 0, stream>>>((const f16*)bufG, SP1, wp, 96, rsum, wrow, b2,
                                              (f16*)bufH, SP2, colsumB, colsqB, 1, N, 135);
    }
    // ---- layer 3 ----
    k_bnfinal<<<1, 256, 0, stream>>>(colsumB, colsqB, bn2g, bn2b, 135, 1.f / (float)N, scale, shift);
    k_prepw<<<(256 * 160 + 255) / 256, 256, 0, stream>>>(W3, scale, wp, 135, 199, 160, 256);
    k_wrow<<<1, 256, 0, stream>>>(W3, shift, wrow, 135, 199, 256);
    k_gather_h<<<(N + 3) / 4, 256, 0, stream>>>(bufH, SP2, 34, rs, deg, csr_s, csr_w, bufG, N, 1);
    {
        dim3 grid(GB, 4);
        k_gemm_mfma<<<grid, 256, 0, stream>>>((const f16*)bufG, SP2, wp, 160, rsum, wrow, b3,
                                              (f16*)bufH, SP3, colsumB, colsqB, 0, N, 199);
    }

    // ---- pool + head ----
    k_pool_h<<<NB, 256, 0, stream>>>(bufH, SP3, batch, N, 199, pooled);
    k_bounds<<<(N + 255) / 256, 256, 0, stream>>>(batch, N, gstart, gend);
    k_mlp<<<G, 64, 0, stream>>>(pooled, gstart, gend, Wl1, bl1, Wl2, bl2, (float*)d_out, 199);
}

// Round 6
// 782.845 us; speedup vs baseline: 3.1973x; 1.0327x over previous
//
#include <hip/hip_runtime.h>
#include <hip/hip_fp16.h>

#define EPSV 1e-5f

typedef _Float16 f16;
typedef f16 half8 __attribute__((ext_vector_type(8)));
typedef float f32x4 __attribute__((ext_vector_type(4)));

// ---------------- degree / CSR construction ----------------

// deg pre-zeroed by memset; counts edges + self loops in one pass
__global__ void k_count(const int* __restrict__ dst, int E, int N, int* __restrict__ deg) {
    int i = blockIdx.x * blockDim.x + threadIdx.x;
    if (i >= E + N) return;
    int d = (i < E) ? dst[i] : (i - E);
    atomicAdd(&deg[d], 1);
}

__global__ void k_disqrt(const int* __restrict__ deg, float* __restrict__ disq, int N) {
    int n = blockIdx.x * blockDim.x + threadIdx.x;
    if (n < N) disq[n] = rsqrtf((float)deg[n]);
}

__global__ void k_scan1(const int* __restrict__ deg, int N,
                        int* __restrict__ incl, int* __restrict__ bsum) {
    __shared__ int s[256];
    int n = blockIdx.x * 256 + threadIdx.x;
    s[threadIdx.x] = (n < N) ? deg[n] : 0;
    __syncthreads();
    for (int off = 1; off < 256; off <<= 1) {
        int v = (threadIdx.x >= off) ? s[threadIdx.x - off] : 0;
        __syncthreads();
        s[threadIdx.x] += v;
        __syncthreads();
    }
    if (n < N) incl[n] = s[threadIdx.x];
    if (threadIdx.x == 255) bsum[blockIdx.x] = s[255];
}

__global__ void k_scan2(const int* __restrict__ bsum, int NB, int* __restrict__ boff) {
    if (blockIdx.x == 0 && threadIdx.x == 0) {
        int run = 0;
        for (int b = 0; b < NB; ++b) { boff[b] = run; run += bsum[b]; }
    }
}

__global__ void k_scan3(const int* __restrict__ deg, const int* __restrict__ incl,
                        const int* __restrict__ boff, int N,
                        int* __restrict__ rs, int* __restrict__ cur) {
    int n = blockIdx.x * 256 + threadIdx.x;
    if (n < N) {
        int v = incl[n] - deg[n] + boff[blockIdx.x];
        rs[n] = v;
        cur[n] = v;
    }
}

// packed CSR fill: one 8B scattered write per edge (src, fp32 weight)
__global__ void k_fill(const int* __restrict__ src, const int* __restrict__ dst,
                       int E, int N, const float* __restrict__ disq,
                       int* __restrict__ cur, int2* __restrict__ csr_sw) {
    int i = blockIdx.x * blockDim.x + threadIdx.x;
    int total = E + N;
    if (i >= total) return;
    int s, d;
    if (i < E) { s = src[i]; d = dst[i]; }
    else       { s = i - E; d = s; }
    int slot = atomicAdd(&cur[d], 1);
    int2 sw;
    sw.x = s;
    sw.y = __float_as_int(disq[s] * disq[d]);
    csr_sw[slot] = sw;
}

// ---------------- BN stats for layer 0 input x (width 7) ----------------

__global__ void k_bnstats(const float* __restrict__ H, int N, int C, int SP,
                          float* __restrict__ colsum, float* __restrict__ colsq) {
    int j = threadIdx.x;
    if (j >= C) return;
    int r0 = blockIdx.x * 256;
    int rend = r0 + 256; if (rend > N) rend = N;
    float s = 0.f, q = 0.f;
    for (int r = r0; r < rend; ++r) {
        float v = H[(size_t)r * SP + j];
        s += v;
        q += v * v;
    }
    atomicAdd(&colsum[j], s);
    atomicAdd(&colsq[j], q);
}

__global__ void k_bnfinal(const float* __restrict__ colsum, const float* __restrict__ colsq,
                          const float* __restrict__ g, const float* __restrict__ b,
                          int C, float invN,
                          float* __restrict__ scale, float* __restrict__ shift) {
    int i = threadIdx.x;
    if (i < C) {
        float m = colsum[i] * invN;
        float v = colsq[i] * invN - m * m;
        float rstd = rsqrtf(fmaxf(v, 0.f) + EPSV);
        float sc = rstd * g[i];
        scale[i] = sc;
        shift[i] = b[i] - m * sc;
    }
}

// ---- per-layer weight prep: Wp_t[n][k] = fp16(scale[k] * W[k][n]), zero-padded ----

__global__ void k_prepw(const float* __restrict__ W, const float* __restrict__ scale,
                        f16* __restrict__ Wp, int Cin, int Cout, int KP, int NP) {
    int idx = blockIdx.x * blockDim.x + threadIdx.x;
    if (idx >= NP * KP) return;
    int n = idx / KP;
    int k = idx - n * KP;
    float v = 0.f;
    if (k < Cin && n < Cout) v = scale[k] * W[(size_t)k * Cout + n];
    Wp[idx] = (f16)v;
}

__global__ void k_wrow(const float* __restrict__ W, const float* __restrict__ shift,
                       float* __restrict__ wrow, int Cin, int Cout, int NP) {
    int c = blockIdx.x * blockDim.x + threadIdx.x;
    if (c >= NP) return;
    float acc = 0.f;
    if (c < Cout)
        for (int k = 0; k < Cin; ++k) acc += shift[k] * W[(size_t)k * Cout + c];
    wrow[c] = acc;
}

// ---------------- pad x [N,7] -> xp [N,8] fp32 ----------------

__global__ void k_padx(const float* __restrict__ x, float* __restrict__ xp, int N) {
    int n = blockIdx.x * blockDim.x + threadIdx.x;
    if (n >= N) return;
    float4 a, b;
    a.x = x[(size_t)n * 7 + 0]; a.y = x[(size_t)n * 7 + 1];
    a.z = x[(size_t)n * 7 + 2]; a.w = x[(size_t)n * 7 + 3];
    b.x = x[(size_t)n * 7 + 4]; b.y = x[(size_t)n * 7 + 5];
    b.z = x[(size_t)n * 7 + 6]; b.w = 0.f;
    *(float4*)(xp + (size_t)n * 8) = a;
    *(float4*)(xp + (size_t)n * 8 + 4) = b;
}

// ---------------- gathers: G = S . X ----------------

// width-8 fp32 input; also emits rsum[n] = sum_e w_e (fused k_rsum)
__global__ void k_gather8(const float* __restrict__ xp, const int2* __restrict__ csr_sw,
                          const int* __restrict__ rs, const int* __restrict__ deg,
                          __half* __restrict__ out, float* __restrict__ rsum, int N) {
    int n = blockIdx.x * blockDim.x + threadIdx.x;
    if (n >= N) return;
    int e0 = rs[n], eend = e0 + deg[n];
    float a0 = 0.f, a1 = 0.f, a2 = 0.f, a3 = 0.f, a4 = 0.f, a5 = 0.f, a6 = 0.f, a7 = 0.f;
    float ws = 0.f;
    for (int e = e0; e < eend; ++e) {
        int2 sw = csr_sw[e];
        int s = sw.x;
        float w = __int_as_float(sw.y);
        ws += w;
        float4 r0 = *(const float4*)(xp + (size_t)s * 8);
        float4 r1 = *(const float4*)(xp + (size_t)s * 8 + 4);
        a0 = fmaf(w, r0.x, a0); a1 = fmaf(w, r0.y, a1);
        a2 = fmaf(w, r0.z, a2); a3 = fmaf(w, r0.w, a3);
        a4 = fmaf(w, r1.x, a4); a5 = fmaf(w, r1.y, a5);
        a6 = fmaf(w, r1.z, a6); a7 = fmaf(w, r1.w, a7);
    }
    rsum[n] = ws;
    __half h[8];
    h[0] = __float2half(a0); h[1] = __float2half(a1);
    h[2] = __float2half(a2); h[3] = __float2half(a3);
    h[4] = __float2half(a4); h[5] = __float2half(a5);
    h[6] = __float2half(a6); h[7] = __float2half(a7);
    *(float4*)(out + (size_t)n * 8) = *(float4*)h;
}

// generic fp16 gather; npw nodes per wave (1 or 2), 4 halfs per lane
__global__ __launch_bounds__(256) void k_gather_h(
    const __half* __restrict__ A, int SPh, int CH,
    const int* __restrict__ rs, const int* __restrict__ deg,
    const int2* __restrict__ csr_sw,
    __half* __restrict__ out, int N, int npw) {
    int wave = threadIdx.x >> 6;
    int lane = threadIdx.x & 63;
    int sub, lsub;
    if (npw == 2) { sub = lane >> 5; lsub = lane & 31; }
    else          { sub = 0;         lsub = lane; }
    int n = (blockIdx.x * 4 + wave) * npw + sub;
    if (n >= N) return;
    int c0 = lsub * 4;
    bool active = lsub < CH;
    int cc = active ? c0 : 0;

    int e0 = rs[n];
    int eend = e0 + deg[n];
    float acc0 = 0.f, acc1 = 0.f, acc2 = 0.f, acc3 = 0.f;

    int e = e0;
    for (; e + 4 <= eend; e += 4) {
        int2 sw0 = csr_sw[e + 0], sw1 = csr_sw[e + 1], sw2 = csr_sw[e + 2], sw3 = csr_sw[e + 3];
        float w0 = __int_as_float(sw0.y), w1 = __int_as_float(sw1.y);
        float w2 = __int_as_float(sw2.y), w3 = __int_as_float(sw3.y);
        float2 r0 = *(const float2*)(A + (size_t)sw0.x * SPh + cc);
        float2 r1 = *(const float2*)(A + (size_t)sw1.x * SPh + cc);
        float2 r2 = *(const float2*)(A + (size_t)sw2.x * SPh + cc);
        float2 r3 = *(const float2*)(A + (size_t)sw3.x * SPh + cc);
        {
            float2 f01 = __half22float2(((const __half2*)&r0)[0]);
            float2 f23 = __half22float2(((const __half2*)&r0)[1]);
            acc0 = fmaf(w0, f01.x, acc0); acc1 = fmaf(w0, f01.y, acc1);
            acc2 = fmaf(w0, f23.x, acc2); acc3 = fmaf(w0, f23.y, acc3);
        }
        {
            float2 f01 = __half22float2(((const __half2*)&r1)[0]);
            float2 f23 = __half22float2(((const __half2*)&r1)[1]);
            acc0 = fmaf(w1, f01.x, acc0); acc1 = fmaf(w1, f01.y, acc1);
            acc2 = fmaf(w1, f23.x, acc2); acc3 = fmaf(w1, f23.y, acc3);
        }
        {
            float2 f01 = __half22float2(((const __half2*)&r2)[0]);
            float2 f23 = __half22float2(((const __half2*)&r2)[1]);
            acc0 = fmaf(w2, f01.x, acc0); acc1 = fmaf(w2, f01.y, acc1);
            acc2 = fmaf(w2, f23.x, acc2); acc3 = fmaf(w2, f23.y, acc3);
        }
        {
            float2 f01 = __half22float2(((const __half2*)&r3)[0]);
            float2 f23 = __half22float2(((const __half2*)&r3)[1]);
            acc0 = fmaf(w3, f01.x, acc0); acc1 = fmaf(w3, f01.y, acc1);
            acc2 = fmaf(w3, f23.x, acc2); acc3 = fmaf(w3, f23.y, acc3);
        }
    }
    for (; e < eend; ++e) {
        int2 sw = csr_sw[e];
        float w = __int_as_float(sw.y);
        float2 r = *(const float2*)(A + (size_t)sw.x * SPh + cc);
        float2 f01 = __half22float2(((const __half2*)&r)[0]);
        float2 f23 = __half22float2(((const __half2*)&r)[1]);
        acc0 = fmaf(w, f01.x, acc0); acc1 = fmaf(w, f01.y, acc1);
        acc2 = fmaf(w, f23.x, acc2); acc3 = fmaf(w, f23.y, acc3);
    }

    if (active) {
        __half2 h01 = __floats2half2_rn(acc0, acc1);
        __half2 h23 = __floats2half2_rn(acc2, acc3);
        float2 packed;
        ((__half2*)&packed)[0] = h01;
        ((__half2*)&packed)[1] = h23;
        *(float2*)(out + (size_t)n * SPh + c0) = packed;
    }
}

// ------------- MFMA GEMM: H = relu(G @ Wp_t^T + rsum (x) wrow + bias) -------------

__global__ __launch_bounds__(256) void k_gemm_mfma(
    const f16* __restrict__ A, int SPa,
    const f16* __restrict__ Bt, int KP,
    const float* __restrict__ rsum, const float* __restrict__ wrow,
    const float* __restrict__ bias,
    f16* __restrict__ out, int SPo,
    float* __restrict__ colsum, float* __restrict__ colsq, int do_stats,
    int N, int Cout) {
    __shared__ f16 As[128][40];
    __shared__ float s_sum[64];
    __shared__ float s_sq[64];
    const int r0 = blockIdx.x * 128;
    const int c0 = blockIdx.y * 64;
    const int t = threadIdx.x;
    const int wave = t >> 6, lane = t & 63;
    const int l15 = lane & 15, quad = lane >> 4;

    if (t < 64) { s_sum[t] = 0.f; s_sq[t] = 0.f; }

    f32x4 zero4 = {0.f, 0.f, 0.f, 0.f};
    f32x4 acc[2][4];
#pragma unroll
    for (int mi = 0; mi < 2; ++mi)
#pragma unroll
        for (int ni = 0; ni < 4; ++ni) acc[mi][ni] = zero4;

    const int KT = KP >> 5;
    for (int kt = 0; kt < KT; ++kt) {
        int k0 = kt * 32;
        {
            int kcol = (t & 7) * 4;
            int rbase = t >> 3;
            int gk = k0 + kcol;
            bool kok = (gk + 4 <= SPa);
#pragma unroll
            for (int i = 0; i < 4; ++i) {
                int row = rbase + i * 32;
                int gr = r0 + row;
                ushort4 v = {0, 0, 0, 0};
                if (gr < N && kok)
                    v = *(const ushort4*)(A + (size_t)gr * SPa + gk);
                *(ushort4*)&As[row][kcol] = v;
            }
        }
        __syncthreads();
        half8 a0 = *(const half8*)&As[wave * 32 + l15][quad * 8];
        half8 a1 = *(const half8*)&As[wave * 32 + 16 + l15][quad * 8];
#pragma unroll
        for (int ni = 0; ni < 4; ++ni) {
            half8 b = *(const half8*)(Bt + (size_t)(c0 + ni * 16 + l15) * KP + k0 + quad * 8);
            acc[0][ni] = __builtin_amdgcn_mfma_f32_16x16x32_f16(a0, b, acc[0][ni], 0, 0, 0);
            acc[1][ni] = __builtin_amdgcn_mfma_f32_16x16x32_f16(a1, b, acc[1][ni], 0, 0, 0);
        }
        __syncthreads();
    }

    float wr[4], bi[4];
#pragma unroll
    for (int ni = 0; ni < 4; ++ni) {
        int gc = c0 + ni * 16 + l15;
        wr[ni] = wrow[gc];
        bi[ni] = (gc < Cout) ? bias[gc] : 0.f;
    }
    float ps[4] = {}, pq[4] = {};
#pragma unroll
    for (int mi = 0; mi < 2; ++mi) {
#pragma unroll
        for (int reg = 0; reg < 4; ++reg) {
            int gr = r0 + wave * 32 + mi * 16 + quad * 4 + reg;
            if (gr >= N) continue;
            float rsv = rsum[gr];
#pragma unroll
            for (int ni = 0; ni < 4; ++ni) {
                int gc = c0 + ni * 16 + l15;
                float o = acc[mi][ni][reg] + rsv * wr[ni] + bi[ni];
                o = fmaxf(o, 0.f);
                if (gc >= Cout) o = 0.f;
                ps[ni] += o; pq[ni] += o * o;
                if (gc < SPo) out[(size_t)gr * SPo + gc] = (f16)o;
            }
        }
    }
    if (do_stats) {
#pragma unroll
        for (int ni = 0; ni < 4; ++ni) {
            int cl = ni * 16 + l15;
            atomicAdd(&s_sum[cl], ps[ni]);
            atomicAdd(&s_sq[cl], pq[ni]);
        }
        __syncthreads();
        if (t < 64 && c0 + t < Cout) {
            atomicAdd(&colsum[c0 + t], s_sum[t]);
            atomicAdd(&colsq[c0 + t], s_sq[t]);
        }
    }
}

// ---------------- mean pool (fp16 input, batch is sorted) ----------------

__global__ void k_pool_h(const __half* __restrict__ H, int SP, const int* __restrict__ batch,
                         int N, int C, float* __restrict__ pooled) {
    __shared__ int sb[256];
    int r0 = blockIdx.x * 256;
    int rows = N - r0; if (rows > 256) rows = 256;
    if (threadIdx.x < rows) sb[threadIdx.x] = batch[r0 + threadIdx.x];
    __syncthreads();
    int c = threadIdx.x;
    if (c >= C) return;
    int cg = sb[0];
    float acc = 0.f;
    for (int r = 0; r < rows; ++r) {
        int g = sb[r];
        if (g != cg) { atomicAdd(&pooled[cg * C + c], acc); acc = 0.f; cg = g; }
        acc += __half2float(H[(size_t)(r0 + r) * SP + c]);
    }
    atomicAdd(&pooled[cg * C + c], acc);
}

__global__ void k_bounds(const int* __restrict__ batch, int N,
                         int* __restrict__ gstart, int* __restrict__ gend) {
    int n = blockIdx.x * blockDim.x + threadIdx.x;
    if (n >= N) return;
    int g = batch[n];
    if (n == 0 || batch[n - 1] != g) gstart[g] = n;
    if (n == N - 1 || batch[n + 1] != g) gend[g] = n + 1;
}

// ---------------- head MLP ----------------

__global__ void k_mlp(const float* __restrict__ pooled, const int* __restrict__ gstart,
                      const int* __restrict__ gend,
                      const float* __restrict__ Wl1, const float* __restrict__ bl1,
                      const float* __restrict__ Wl2, const float* __restrict__ bl2,
                      float* __restrict__ out, int C) {
    __shared__ float p[199];
    __shared__ float t1[49];
    int g = blockIdx.x;
    int cnt = gend[g] - gstart[g];
    float inv = 1.f / (float)(cnt > 1 ? cnt : 1);
    for (int k = threadIdx.x; k < C; k += blockDim.x) p[k] = pooled[g * C + k] * inv;
    __syncthreads();
    if (threadIdx.x < 49) {
        float acc = bl1[threadIdx.x];
        for (int k = 0; k < C; ++k) acc += p[k] * Wl1[k * 49 + threadIdx.x];
        t1[threadIdx.x] = acc;
    }
    __syncthreads();
    if (threadIdx.x < 2) {
        float acc = bl2[threadIdx.x];
        for (int k = 0; k < 49; ++k) acc += t1[k] * Wl2[k * 2 + threadIdx.x];
        out[g * 2 + threadIdx.x] = acc;
    }
}

// ---------------- launch ----------------

extern "C" void kernel_launch(void* const* d_in, const int* in_sizes, int n_in,
                              void* d_out, int out_size, void* d_ws, size_t ws_size,
                              hipStream_t stream) {
    const float* x     = (const float*)d_in[0];
    const int*   ei    = (const int*)d_in[1];
    const int*   batch = (const int*)d_in[2];
    const float* bn0g = (const float*)d_in[3];
    const float* bn0b = (const float*)d_in[4];
    const float* bn1g = (const float*)d_in[5];
    const float* bn1b = (const float*)d_in[6];
    const float* bn2g = (const float*)d_in[7];
    const float* bn2b = (const float*)d_in[8];
    const float* W1  = (const float*)d_in[9];
    const float* b1  = (const float*)d_in[10];
    const float* W2  = (const float*)d_in[11];
    const float* b2  = (const float*)d_in[12];
    const float* W3  = (const float*)d_in[13];
    const float* b3  = (const float*)d_in[14];
    const float* Wl1 = (const float*)d_in[15];
    const float* bl1 = (const float*)d_in[16];
    const float* Wl2 = (const float*)d_in[17];
    const float* bl2 = (const float*)d_in[18];

    const int N = in_sizes[0] / 7;
    const int E = in_sizes[1] / 2;
    const int EN = E + N;
    const int G = out_size / 2;
    const int NB = (N + 255) / 256;

    const int SP1 = 72, SP2 = 136, SP3 = 200;

    const int* src = ei;
    const int* dst = ei + E;

    char* w = (char*)d_ws;
    auto alloc = [&](size_t bytes) -> void* {
        void* p = (void*)w;
        w += ((bytes + 255) / 256) * 256;
        return p;
    };
    __half* bufH = (__half*)alloc((size_t)N * SP3 * sizeof(__half));
    __half* bufG = (__half*)alloc((size_t)N * SP2 * sizeof(__half));
    f16*    wp   = (f16*)  alloc((size_t)256 * 160 * sizeof(f16));
    float*  wrow = (float*)alloc(256 * sizeof(float));
    float* xp    = (float*)alloc((size_t)N * 8 * sizeof(float));
    float* disq  = (float*)alloc((size_t)N * sizeof(float));
    float* rsum  = (float*)alloc((size_t)N * sizeof(float));
    int*   deg   = (int*)  alloc((size_t)N * sizeof(int));
    int*   rs    = (int*)  alloc((size_t)N * sizeof(int));
    int*   cur   = (int*)  alloc((size_t)N * sizeof(int));
    int2*  csr_sw= (int2*) alloc((size_t)EN * sizeof(int2));
    float* colsum0 = (float*)alloc(256 * sizeof(float));
    float* colsq0  = (float*)alloc(256 * sizeof(float));
    float* colsumA = (float*)alloc(256 * sizeof(float));
    float* colsqA  = (float*)alloc(256 * sizeof(float));
    float* colsumB = (float*)alloc(256 * sizeof(float));
    float* colsqB  = (float*)alloc(256 * sizeof(float));
    float* scale = (float*)alloc(256 * sizeof(float));
    float* shift = (float*)alloc(256 * sizeof(float));
    float* pooled= (float*)alloc((size_t)G * 199 * sizeof(float));
    int*   gstart= (int*)  alloc((size_t)G * sizeof(int));
    int*   gend  = (int*)  alloc((size_t)G * sizeof(int));
    int*   bsum  = (int*)  alloc((size_t)NB * sizeof(int));
    int*   boff  = (int*)  alloc((size_t)NB * sizeof(int));

    hipMemsetAsync(deg, 0, (size_t)N * sizeof(int), stream);
    hipMemsetAsync(colsum0, 0, 6 * 256 * sizeof(float), stream);
    hipMemsetAsync(pooled, 0, (size_t)G * 199 * sizeof(float), stream);
    hipMemsetAsync(gstart, 0, G * sizeof(int), stream);
    hipMemsetAsync(gend, 0, G * sizeof(int), stream);

    // ---- degree + CSR ----
    k_count<<<(EN + 255) / 256, 256, 0, stream>>>(dst, E, N, deg);
    k_disqrt<<<(N + 255) / 256, 256, 0, stream>>>(deg, disq, N);
    k_scan1<<<NB, 256, 0, stream>>>(deg, N, rs, bsum);
    k_scan2<<<1, 1, 0, stream>>>(bsum, NB, boff);
    k_scan3<<<NB, 256, 0, stream>>>(deg, rs, boff, N, rs, cur);
    k_fill<<<(EN + 255) / 256, 256, 0, stream>>>(src, dst, E, N, disq, cur, csr_sw);

    const int GB = (N + 127) / 128;

    // ---- layer 1 ----
    k_bnstats<<<NB, 256, 0, stream>>>(x, N, 7, 7, colsum0, colsq0);
    k_bnfinal<<<1, 256, 0, stream>>>(colsum0, colsq0, bn0g, bn0b, 7, 1.f / (float)N, scale, shift);
    k_prepw<<<(128 * 32 + 255) / 256, 256, 0, stream>>>(W1, scale, wp, 7, 71, 32, 128);
    k_wrow<<<1, 128, 0, stream>>>(W1, shift, wrow, 7, 71, 128);
    k_padx<<<(N + 255) / 256, 256, 0, stream>>>(x, xp, N);
    k_gather8<<<(N + 255) / 256, 256, 0, stream>>>(xp, csr_sw, rs, deg, bufG, rsum, N);
    {
        dim3 grid(GB, 2);
        k_gemm_mfma<<<grid, 256, 0, stream>>>((const f16*)bufG, 8, wp, 32, rsum, wrow, b1,
                                              (f16*)bufH, SP1, colsumA, colsqA, 1, N, 71);
    }
    // ---- layer 2 ----
    k_bnfinal<<<1, 256, 0, stream>>>(colsumA, colsqA, bn1g, bn1b, 71, 1.f / (float)N, scale, shift);
    k_prepw<<<(192 * 96 + 255) / 256, 256, 0, stream>>>(W2, scale, wp, 71, 135, 96, 192);
    k_wrow<<<1, 192, 0, stream>>>(W2, shift, wrow, 71, 135, 192);
    k_gather_h<<<(N + 7) / 8, 256, 0, stream>>>(bufH, SP1, 18, rs, deg, csr_sw, bufG, N, 2);
    {
        dim3 grid(GB, 3);
        k_gemm_mfma<<<grid, 256, 0, stream>>>((const f16*)bufG, SP1, wp, 96, rsum, wrow, b2,
                                              (f16*)bufH, SP2, colsumB, colsqB, 1, N, 135);
    }
    // ---- layer 3 ----
    k_bnfinal<<<1, 256, 0, stream>>>(colsumB, colsqB, bn2g, bn2b, 135, 1.f / (float)N, scale, shift);
    k_prepw<<<(256 * 160 + 255) / 256, 256, 0, stream>>>(W3, scale, wp, 135, 199, 160, 256);
    k_wrow<<<1, 256, 0, stream>>>(W3, shift, wrow, 135, 199, 256);
    k_gather_h<<<(N + 3) / 4, 256, 0, stream>>>(bufH, SP2, 34, rs, deg, csr_sw, bufG, N, 1);
    {
        dim3 grid(GB, 4);
        k_gemm_mfma<<<grid, 256, 0, stream>>>((const f16*)bufG, SP2, wp, 160, rsum, wrow, b3,
                                              (f16*)bufH, SP3, colsumB, colsqB, 0, N, 199);
    }

    // ---- pool + head ----
    k_pool_h<<<NB, 256, 0, stream>>>(bufH, SP3, batch, N, 199, pooled);
    k_bounds<<<(N + 255) / 256, 256, 0, stream>>>(batch, N, gstart, gend);
    k_mlp<<<G, 64, 0, stream>>>(pooled, gstart, gend, Wl1, bl1, Wl2, bl2, (float*)d_out, 199);
}